// Round 1
// baseline (336.159 us; speedup 1.0000x reference)
//
#include <hip/hip_runtime.h>

typedef unsigned int uint32;
typedef __bf16 bf16x8 __attribute__((ext_vector_type(8)));
typedef float f32x4 __attribute__((ext_vector_type(4)));

typedef __attribute__((address_space(1))) unsigned int as1_uint;
typedef __attribute__((address_space(3))) unsigned int as3_uint;

// ---------- constants ----------
#define BATCH 4096
#define D0D1 2048
#define MM 1600
#define NCHUNKS 20
#define RANK 15
#define CSIZE 80
#define TDIM 1200   // SIZE*RANK
#define NOUT 3000

__device__ __forceinline__ unsigned short f2bf(float f) {
  unsigned int u = __builtin_bit_cast(unsigned int, f);
  u = (u + 0x7fffu + ((u >> 16) & 1u)) >> 16;
  return (unsigned short)u;
}

__device__ __forceinline__ void gload_lds16(const void* g, void* lds) {
  __builtin_amdgcn_global_load_lds((as1_uint*)g, (as3_uint*)lds, 16, 0, 0);
}

// ---------- cast f32 -> bf16, 8 elems/thread ----------
__global__ __launch_bounds__(256) void cast_bf16_k(const float* __restrict__ src,
                                                   unsigned short* __restrict__ dst, int n) {
  int i = (blockIdx.x * 256 + threadIdx.x) * 8;
  if (i >= n) return;
  float4 v0 = *(const float4*)(src + i);
  float4 v1 = *(const float4*)(src + i + 4);
  uint4 o;
  o.x = (uint32)f2bf(v0.x) | ((uint32)f2bf(v0.y) << 16);
  o.y = (uint32)f2bf(v0.z) | ((uint32)f2bf(v0.w) << 16);
  o.z = (uint32)f2bf(v1.x) | ((uint32)f2bf(v1.y) << 16);
  o.w = (uint32)f2bf(v1.z) | ((uint32)f2bf(v1.w) << 16);
  *(uint4*)(dst + i) = o;
}

// ---------- NT GEMM core (m97 structure): C[M,N] = A[M,K] * B[N,K]^T + bias ----------
// 128x128 tile, BK=32, 4 waves (2x2 of 64x64), 16x16x32 bf16 MFMA.
template <bool BF16OUT>
__device__ __forceinline__ void gemm_core(const unsigned short* __restrict__ A,
                                          const unsigned short* __restrict__ B,
                                          const float* __restrict__ bias,
                                          void* __restrict__ Cv,
                                          unsigned short* As, unsigned short* Bs,
                                          int M, int N, int K, int bm0, int bn0) {
  const int tid = threadIdx.x;
  const int wave = tid >> 6, lane = tid & 63;
  const int wr = (wave >> 1) * 64, wc = (wave & 1) * 64;
  const int lrow = lane & 15, lkg = (lane >> 4) * 8;

  f32x4 acc[4][4];
#pragma unroll
  for (int m = 0; m < 4; ++m)
#pragma unroll
    for (int n = 0; n < 4; ++n) acc[m][n] = 0.f;

  for (int kt = 0; kt < K; kt += 32) {
#pragma unroll
    for (int q = 0; q < 2; ++q) {
      int ci = wave * 2 + q;           // 0..7 : 1024-byte chunk of the 8 KB tile
      int e = ci * 512 + lane * 8;     // element offset (ushort) this lane supplies
      int row = e >> 5, kk = e & 31;
      gload_lds16(A + (size_t)(bm0 + row) * K + kt + kk, (char*)As + ci * 1024);
      int brow = bn0 + row;
      if (brow > N - 1) brow = N - 1;  // clamp keeps loads in-bounds for ragged N
      gload_lds16(B + (size_t)brow * K + kt + kk, (char*)Bs + ci * 1024);
    }
    __syncthreads();   // compiler drains vmcnt before s_barrier

    bf16x8 a[4], b[4];
#pragma unroll
    for (int m = 0; m < 4; ++m)
      a[m] = *reinterpret_cast<const bf16x8*>(&As[(wr + m * 16 + lrow) * 32 + lkg]);
#pragma unroll
    for (int n = 0; n < 4; ++n)
      b[n] = *reinterpret_cast<const bf16x8*>(&Bs[(wc + n * 16 + lrow) * 32 + lkg]);
#pragma unroll
    for (int m = 0; m < 4; ++m)
#pragma unroll
      for (int n = 0; n < 4; ++n)
        acc[m][n] = __builtin_amdgcn_mfma_f32_16x16x32_bf16(a[m], b[n], acc[m][n], 0, 0, 0);
    __syncthreads();
  }

  // epilogue: C/D layout col=lane&15, row=(lane>>4)*4+j  [m89 verified]
#pragma unroll
  for (int n = 0; n < 4; ++n) {
    int col = bn0 + wc + n * 16 + lrow;
    if (col < N) {
      float bv = bias[col];
#pragma unroll
      for (int m = 0; m < 4; ++m) {
#pragma unroll
        for (int j = 0; j < 4; ++j) {
          int row = bm0 + wr + m * 16 + (lane >> 4) * 4 + j;
          float v = acc[m][n][j] + bv;
          if (BF16OUT)
            ((unsigned short*)Cv)[(size_t)row * N + col] = f2bf(v);
          else
            ((float*)Cv)[(size_t)row * N + col] = v;
        }
      }
    }
  }
}

__global__ __launch_bounds__(256) void gemm_dual_bf16(
    const unsigned short* A0, const unsigned short* B0, const float* bias0, unsigned short* C0,
    const unsigned short* A1, const unsigned short* B1, const float* bias1, unsigned short* C1,
    int M, int N, int K) {
  __shared__ unsigned short As[128 * 32];
  __shared__ unsigned short Bs[128 * 32];
  const unsigned short* A = blockIdx.z ? A1 : A0;
  const unsigned short* B = blockIdx.z ? B1 : B0;
  const float* bias = blockIdx.z ? bias1 : bias0;
  unsigned short* C = blockIdx.z ? C1 : C0;
  gemm_core<true>(A, B, bias, C, As, Bs, M, N, K, blockIdx.y * 128, blockIdx.x * 128);
}

__global__ __launch_bounds__(256) void gemm_f32out(
    const unsigned short* A, const unsigned short* B, const float* bias, float* C,
    int M, int N, int K) {
  __shared__ unsigned short As[128 * 32];
  __shared__ unsigned short Bs[128 * 32];
  gemm_core<false>(A, B, bias, C, As, Bs, M, N, K, blockIdx.y * 128, blockIdx.x * 128);
}

// ---------- stage 2: per-chunk rank MM + bilinear + signed sqrt + L2 norm ----------
// block = (chunk c, 64-row batch tile). 4 waves, each wave owns 16 batch rows.
// K=80 zero-padded to 96 so three 16x16x32 MFMA k-frags cover it.
__global__ __launch_bounds__(256) void chunk_fuse(
    const unsigned short* __restrict__ hb0, const unsigned short* __restrict__ hb1,
    const unsigned short* __restrict__ mWb0, const float* __restrict__ mb0,
    const unsigned short* __restrict__ mWb1, const float* __restrict__ mb1,
    unsigned short* __restrict__ zb) {
  const int c = blockIdx.x, bt = blockIdx.y;
  __shared__ unsigned short h0s[64][96], h1s[64][96];
  __shared__ unsigned short w0s[80][96], w1s[80][96];
  const int tid = threadIdx.x, wave = tid >> 6, lane = tid & 63;
  const int lrow = lane & 15, lj = lane >> 4;

  // zero the K-pad columns [80,96)
  for (int i = tid; i < 64 * 8; i += 256) {
    int r = i >> 3, m = i & 7;
    ((uint32*)&h0s[r][80])[m] = 0;
    ((uint32*)&h1s[r][80])[m] = 0;
  }
  for (int i = tid; i < 80 * 8; i += 256) {
    int r = i >> 3, m = i & 7;
    ((uint32*)&w0s[r][80])[m] = 0;
    ((uint32*)&w1s[r][80])[m] = 0;
  }
  // load h tiles once: 64 rows x 80 (10 x 16B chunks per row)
  for (int i = tid; i < 640; i += 256) {
    int r = i / 10, ko = (i % 10) * 8;
    size_t goff = (size_t)(bt * 64 + r) * MM + c * CSIZE + ko;
    *(uint4*)&h0s[r][ko] = *(const uint4*)(hb0 + goff);
    *(uint4*)&h1s[r][ko] = *(const uint4*)(hb1 + goff);
  }

  f32x4 zacc[5];
#pragma unroll
  for (int n = 0; n < 5; ++n) zacc[n] = 0.f;

  for (int r = 0; r < RANK; ++r) {
    __syncthreads();  // protect previous iter's w reads (also covers init on r=0)
    for (int i = tid; i < 800; i += 256) {
      int t = i / 10, ko = (i % 10) * 8;
      size_t goff = ((size_t)(c * TDIM + r * CSIZE + t)) * CSIZE + ko;
      *(uint4*)&w0s[t][ko] = *(const uint4*)(mWb0 + goff);
      *(uint4*)&w1s[t][ko] = *(const uint4*)(mWb1 + goff);
    }
    __syncthreads();

    f32x4 y0[5], y1[5];
#pragma unroll
    for (int n = 0; n < 5; ++n) { y0[n] = 0.f; y1[n] = 0.f; }
#pragma unroll
    for (int kf = 0; kf < 3; ++kf) {
      int k = kf * 32 + lj * 8;
      bf16x8 a0 = *(const bf16x8*)&h0s[wave * 16 + lrow][k];
      bf16x8 a1 = *(const bf16x8*)&h1s[wave * 16 + lrow][k];
#pragma unroll
      for (int n = 0; n < 5; ++n) {
        bf16x8 b0v = *(const bf16x8*)&w0s[n * 16 + lrow][k];
        bf16x8 b1v = *(const bf16x8*)&w1s[n * 16 + lrow][k];
        y0[n] = __builtin_amdgcn_mfma_f32_16x16x32_bf16(a0, b0v, y0[n], 0, 0, 0);
        y1[n] = __builtin_amdgcn_mfma_f32_16x16x32_bf16(a1, b1v, y1[n], 0, 0, 0);
      }
    }
    // bias + bilinear product, accumulated in D-fragment layout
#pragma unroll
    for (int n = 0; n < 5; ++n) {
      int s = n * 16 + lrow;
      float bi0 = mb0[c * TDIM + r * CSIZE + s];
      float bi1 = mb1[c * TDIM + r * CSIZE + s];
#pragma unroll
      for (int j = 0; j < 4; ++j)
        zacc[n][j] += (y0[n][j] + bi0) * (y1[n][j] + bi1);
    }
  }

  // signed sqrt, per-row L2 norm over the 80 cols (16 lanes x 5 frags), write bf16
  float g[5][4];
  float ssj[4] = {0.f, 0.f, 0.f, 0.f};
#pragma unroll
  for (int n = 0; n < 5; ++n)
#pragma unroll
    for (int j = 0; j < 4; ++j) {
      float v = zacc[n][j];
      float a = sqrtf(fabsf(v));
      float gv = v < 0.f ? -a : a;
      g[n][j] = gv;
      ssj[j] += gv * gv;
    }
#pragma unroll
  for (int j = 0; j < 4; ++j) {
    float s = ssj[j];
    s += __shfl_xor(s, 1);
    s += __shfl_xor(s, 2);
    s += __shfl_xor(s, 4);
    s += __shfl_xor(s, 8);
    float nrm = sqrtf(s);
    nrm = nrm > 1e-12f ? nrm : 1e-12f;
    ssj[j] = 1.f / nrm;
  }
#pragma unroll
  for (int n = 0; n < 5; ++n) {
    int s = n * 16 + lrow;
#pragma unroll
    for (int j = 0; j < 4; ++j) {
      int row = bt * 64 + wave * 16 + lj * 4 + j;
      zb[(size_t)row * MM + c * CSIZE + s] = f2bf(g[n][j] * ssj[j]);
    }
  }
}

// ---------- workspace layout (bytes) ----------
#define OFF_XB0   ((size_t)0)
#define OFF_XB1   (OFF_XB0 + (size_t)BATCH * D0D1 * 2)
#define OFF_WB0   (OFF_XB1 + (size_t)BATCH * D0D1 * 2)
#define OFF_WB1   (OFF_WB0 + (size_t)MM * D0D1 * 2)
#define OFF_MWB0  (OFF_WB1 + (size_t)MM * D0D1 * 2)
#define OFF_MWB1  (OFF_MWB0 + (size_t)NCHUNKS * TDIM * CSIZE * 2)
#define OFF_WOUTB (OFF_MWB1 + (size_t)NCHUNKS * TDIM * CSIZE * 2)
#define OFF_HB0   (OFF_WOUTB + (size_t)NOUT * MM * 2)
#define OFF_HB1   (OFF_HB0 + (size_t)BATCH * MM * 2)
#define OFF_ZB    (OFF_HB1 + (size_t)BATCH * MM * 2)
#define WS_NEED   (OFF_ZB + (size_t)BATCH * MM * 2)

extern "C" void kernel_launch(void* const* d_in, const int* in_sizes, int n_in,
                              void* d_out, int out_size, void* d_ws, size_t ws_size,
                              hipStream_t stream) {
  const float* x0   = (const float*)d_in[0];
  const float* x1   = (const float*)d_in[1];
  const float* W0   = (const float*)d_in[2];
  const float* b0   = (const float*)d_in[3];
  const float* W1   = (const float*)d_in[4];
  const float* b1   = (const float*)d_in[5];
  const float* mW0  = (const float*)d_in[6];
  const float* mb0  = (const float*)d_in[7];
  const float* mW1  = (const float*)d_in[8];
  const float* mb1  = (const float*)d_in[9];
  const float* Wout = (const float*)d_in[10];
  const float* bout = (const float*)d_in[11];

  if (ws_size < WS_NEED) return;  // need ~103 MB of scratch

  char* ws = (char*)d_ws;
  unsigned short* xb0   = (unsigned short*)(ws + OFF_XB0);
  unsigned short* xb1   = (unsigned short*)(ws + OFF_XB1);
  unsigned short* Wb0   = (unsigned short*)(ws + OFF_WB0);
  unsigned short* Wb1   = (unsigned short*)(ws + OFF_WB1);
  unsigned short* mWb0  = (unsigned short*)(ws + OFF_MWB0);
  unsigned short* mWb1  = (unsigned short*)(ws + OFF_MWB1);
  unsigned short* Woutb = (unsigned short*)(ws + OFF_WOUTB);
  unsigned short* hb0   = (unsigned short*)(ws + OFF_HB0);
  unsigned short* hb1   = (unsigned short*)(ws + OFF_HB1);
  unsigned short* zb    = (unsigned short*)(ws + OFF_ZB);

  auto cast = [&](const float* s, unsigned short* d, int n) {
    int blocks = (n / 8 + 255) / 256;
    hipLaunchKernelGGL(cast_bf16_k, dim3(blocks), dim3(256), 0, stream, s, d, n);
  };
  cast(x0, xb0, BATCH * D0D1);
  cast(x1, xb1, BATCH * D0D1);
  cast(W0, Wb0, MM * D0D1);
  cast(W1, Wb1, MM * D0D1);
  cast(mW0, mWb0, NCHUNKS * TDIM * CSIZE);
  cast(mW1, mWb1, NCHUNKS * TDIM * CSIZE);
  cast(Wout, Woutb, NOUT * MM);

  // stage 1: h0,h1 = x@W^T + b  -> bf16 [4096][1600]
  hipLaunchKernelGGL(gemm_dual_bf16, dim3(13, 32, 2), dim3(256), 0, stream,
                     xb0, Wb0, b0, hb0, xb1, Wb1, b1, hb1, BATCH, MM, D0D1);

  // stage 2: chunk MM + bilinear + signed sqrt + L2 norm -> zb bf16 [4096][1600]
  hipLaunchKernelGGL(chunk_fuse, dim3(NCHUNKS, BATCH / 64), dim3(256), 0, stream,
                     hb0, hb1, mWb0, mb0, mWb1, mb1, zb);

  // stage 3: out = zn@Wout^T + bout -> f32 [4096][3000]
  hipLaunchKernelGGL(gemm_f32out, dim3(24, 32), dim3(256), 0, stream,
                     zb, Woutb, bout, (float*)d_out, BATCH, NOUT, MM);
}

// Round 2
// 274.777 us; speedup vs baseline: 1.2234x; 1.2234x over previous
//
#include <hip/hip_runtime.h>

typedef unsigned int uint32;
typedef __bf16 bf16x8 __attribute__((ext_vector_type(8)));
typedef float f32x4 __attribute__((ext_vector_type(4)));

typedef __attribute__((address_space(1))) unsigned int as1_uint;
typedef __attribute__((address_space(3))) unsigned int as3_uint;

// ---------- constants ----------
#define BATCH 4096
#define D0D1 2048
#define MM 1600
#define NCHUNKS 20
#define RANK 15
#define CSIZE 80
#define TDIM 1200   // SIZE*RANK
#define NOUT 3000

// packed weight layout for stage 2: mWP[c][r][tensor][row 0..80][col 0..87] bf16
// row 80 = bias row; cols 80..87 zero pad. stride 88 elems = 176B = 44 words,
// 44 mod 32 = 12 -> 8 distinct bank offsets over 16 rows -> conflict-free b128 reads.
#define WST 88
#define WTROWS 81
#define WTEN (WTROWS * WST)     // 7128 elems per tensor
#define WRANK (2 * WTEN)        // 14256 elems per (c,r) slice
#define WCH (WRANK * 2 / 16)    // 1782 16-byte chunks per slice

__device__ __forceinline__ unsigned short f2bf(float f) {
  unsigned int u = __builtin_bit_cast(unsigned int, f);
  u = (u + 0x7fffu + ((u >> 16) & 1u)) >> 16;
  return (unsigned short)u;
}
__device__ __forceinline__ float bf2f(unsigned short u) {
  return __builtin_bit_cast(float, (uint32)u << 16);
}

__device__ __forceinline__ void gload_lds16(const void* g, void* lds) {
  __builtin_amdgcn_global_load_lds((as1_uint*)g, (as3_uint*)lds, 16, 0, 0);
}

// ---------- cast f32 -> bf16, 8 elems/thread ----------
__global__ __launch_bounds__(256) void cast_bf16_k(const float* __restrict__ src,
                                                   unsigned short* __restrict__ dst, int n) {
  int i = (blockIdx.x * 256 + threadIdx.x) * 8;
  if (i >= n) return;
  float4 v0 = *(const float4*)(src + i);
  float4 v1 = *(const float4*)(src + i + 4);
  uint4 o;
  o.x = (uint32)f2bf(v0.x) | ((uint32)f2bf(v0.y) << 16);
  o.y = (uint32)f2bf(v0.z) | ((uint32)f2bf(v0.w) << 16);
  o.z = (uint32)f2bf(v1.x) | ((uint32)f2bf(v1.y) << 16);
  o.w = (uint32)f2bf(v1.z) | ((uint32)f2bf(v1.w) << 16);
  *(uint4*)(dst + i) = o;
}

// ---------- pack mW + mb into padded conflict-free layout ----------
// grid: (7, RANK, NCHUNKS); thread handles one 16B chunk (8 bf16) of the slice.
__global__ __launch_bounds__(256) void cast_mwp_k(
    const float* __restrict__ mW0, const float* __restrict__ mb0,
    const float* __restrict__ mW1, const float* __restrict__ mb1,
    unsigned short* __restrict__ mWP) {
  const int c = blockIdx.z, r = blockIdx.y;
  int i = blockIdx.x * 256 + threadIdx.x;
  if (i >= WCH) return;
  int e = i * 8;
  int tensor = e / WTEN;
  int rem = e - tensor * WTEN;
  int row = rem / WST;
  int col0 = rem - row * WST;   // multiple of 8; 80 -> pure pad chunk

  float v[8];
  if (col0 >= CSIZE) {
#pragma unroll
    for (int k = 0; k < 8; ++k) v[k] = 0.f;
  } else if (row < CSIZE) {
    const float* src = (tensor ? mW1 : mW0) +
                       ((size_t)c * TDIM + (size_t)r * CSIZE + row) * CSIZE + col0;
#pragma unroll
    for (int k = 0; k < 8; ++k) v[k] = src[k];
  } else {  // bias row
    const float* src = (tensor ? mb1 : mb0) + (size_t)c * TDIM + (size_t)r * CSIZE + col0;
#pragma unroll
    for (int k = 0; k < 8; ++k) v[k] = src[k];
  }
  uint4 o;
  o.x = (uint32)f2bf(v[0]) | ((uint32)f2bf(v[1]) << 16);
  o.y = (uint32)f2bf(v[2]) | ((uint32)f2bf(v[3]) << 16);
  o.z = (uint32)f2bf(v[4]) | ((uint32)f2bf(v[5]) << 16);
  o.w = (uint32)f2bf(v[6]) | ((uint32)f2bf(v[7]) << 16);
  *(uint4*)(mWP + ((size_t)(c * RANK + r)) * WRANK + e) = o;
}

// ---------- NT GEMM core (m97 structure): C[M,N] = A[M,K] * B[N,K]^T + bias ----------
template <bool BF16OUT>
__device__ __forceinline__ void gemm_core(const unsigned short* __restrict__ A,
                                          const unsigned short* __restrict__ B,
                                          const float* __restrict__ bias,
                                          void* __restrict__ Cv,
                                          unsigned short* As, unsigned short* Bs,
                                          int M, int N, int K, int bm0, int bn0) {
  const int tid = threadIdx.x;
  const int wave = tid >> 6, lane = tid & 63;
  const int wr = (wave >> 1) * 64, wc = (wave & 1) * 64;
  const int lrow = lane & 15, lkg = (lane >> 4) * 8;

  f32x4 acc[4][4];
#pragma unroll
  for (int m = 0; m < 4; ++m)
#pragma unroll
    for (int n = 0; n < 4; ++n) acc[m][n] = 0.f;

  for (int kt = 0; kt < K; kt += 32) {
#pragma unroll
    for (int q = 0; q < 2; ++q) {
      int ci = wave * 2 + q;
      int e = ci * 512 + lane * 8;
      int row = e >> 5, kk = e & 31;
      gload_lds16(A + (size_t)(bm0 + row) * K + kt + kk, (char*)As + ci * 1024);
      int brow = bn0 + row;
      if (brow > N - 1) brow = N - 1;
      gload_lds16(B + (size_t)brow * K + kt + kk, (char*)Bs + ci * 1024);
    }
    __syncthreads();

    bf16x8 a[4], b[4];
#pragma unroll
    for (int m = 0; m < 4; ++m)
      a[m] = *reinterpret_cast<const bf16x8*>(&As[(wr + m * 16 + lrow) * 32 + lkg]);
#pragma unroll
    for (int n = 0; n < 4; ++n)
      b[n] = *reinterpret_cast<const bf16x8*>(&Bs[(wc + n * 16 + lrow) * 32 + lkg]);
#pragma unroll
    for (int m = 0; m < 4; ++m)
#pragma unroll
      for (int n = 0; n < 4; ++n)
        acc[m][n] = __builtin_amdgcn_mfma_f32_16x16x32_bf16(a[m], b[n], acc[m][n], 0, 0, 0);
    __syncthreads();
  }

#pragma unroll
  for (int n = 0; n < 4; ++n) {
    int col = bn0 + wc + n * 16 + lrow;
    if (col < N) {
      float bv = bias[col];
#pragma unroll
      for (int m = 0; m < 4; ++m) {
#pragma unroll
        for (int j = 0; j < 4; ++j) {
          int row = bm0 + wr + m * 16 + (lane >> 4) * 4 + j;
          float v = acc[m][n][j] + bv;
          if (BF16OUT)
            ((unsigned short*)Cv)[(size_t)row * N + col] = f2bf(v);
          else
            ((float*)Cv)[(size_t)row * N + col] = v;
        }
      }
    }
  }
}

__global__ __launch_bounds__(256) void gemm_dual_bf16(
    const unsigned short* A0, const unsigned short* B0, const float* bias0, unsigned short* C0,
    const unsigned short* A1, const unsigned short* B1, const float* bias1, unsigned short* C1,
    int M, int N, int K) {
  __shared__ unsigned short As[128 * 32];
  __shared__ unsigned short Bs[128 * 32];
  const unsigned short* A = blockIdx.z ? A1 : A0;
  const unsigned short* B = blockIdx.z ? B1 : B0;
  const float* bias = blockIdx.z ? bias1 : bias0;
  unsigned short* C = blockIdx.z ? C1 : C0;
  gemm_core<true>(A, B, bias, C, As, Bs, M, N, K, blockIdx.y * 128, blockIdx.x * 128);
}

__global__ __launch_bounds__(256) void gemm_f32out(
    const unsigned short* A, const unsigned short* B, const float* bias, float* C,
    int M, int N, int K) {
  __shared__ unsigned short As[128 * 32];
  __shared__ unsigned short Bs[128 * 32];
  gemm_core<false>(A, B, bias, C, As, Bs, M, N, K, blockIdx.y * 128, blockIdx.x * 128);
}

// ---------- stage 2 v2: h in registers, async double-buffered weight staging ----------
// block = (chunk c, 128-row batch tile), 4 waves x 32 rows each.
__global__ __launch_bounds__(256, 2) void chunk_fuse2(
    const unsigned short* __restrict__ hb0, const unsigned short* __restrict__ hb1,
    const unsigned short* __restrict__ mWP, unsigned short* __restrict__ zb) {
  const int c = blockIdx.x, bt = blockIdx.y;
  __shared__ unsigned short wlds[2][WRANK];   // 57,024 B
  const int tid = threadIdx.x, wave = tid >> 6, lane = tid & 63;
  const int lrow = lane & 15, lj = lane >> 4;

  bf16x8 bzero;
  bzero = (__bf16)0.0f;

  // A fragments (h) -> registers, loop-invariant over ranks.
  // kf=2 covers chunk cols 64..95; cols >=80 belong to the next chunk -> zero-mask.
  bf16x8 a0[2][3], a1[2][3];
#pragma unroll
  for (int m = 0; m < 2; ++m)
#pragma unroll
    for (int kf = 0; kf < 3; ++kf) {
      int col = kf * 32 + lj * 8;
      bool valid = col < CSIZE;
      int row = bt * 128 + wave * 32 + m * 16 + lrow;
      size_t base = (size_t)row * MM + c * CSIZE + (valid ? col : 0);
      bf16x8 v0 = *(const bf16x8*)(hb0 + base);
      bf16x8 v1 = *(const bf16x8*)(hb1 + base);
      a0[m][kf] = valid ? v0 : bzero;
      a1[m][kf] = valid ? v1 : bzero;
    }

  const unsigned short* wsrc = mWP + (size_t)(c * RANK) * WRANK;
  // async stage of one (c,r) slice: 7 uniform global_load_lds(16B) per wave
  auto STAGE = [&](int buf, int r) {
    const unsigned short* src = wsrc + (size_t)r * WRANK;
    char* dstb = (char*)&wlds[buf][0];
#pragma unroll
    for (int k = 0; k < 7; ++k) {
      int i = k * 256 + tid;
      if (i < WCH)
        gload_lds16(src + (size_t)i * 8, dstb + (k * 256 + wave * 64) * 16);
    }
  };

  f32x4 zacc[2][5];
#pragma unroll
  for (int m = 0; m < 2; ++m)
#pragma unroll
    for (int n = 0; n < 5; ++n) zacc[m][n] = 0.f;

  STAGE(0, 0);
  for (int r = 0; r < RANK; ++r) {
    int cur = r & 1;
    if (r < RANK - 1) {
      STAGE(cur ^ 1, r + 1);
      asm volatile("s_waitcnt vmcnt(7)" ::: "memory");  // current slice done, next in flight
    } else {
      asm volatile("s_waitcnt vmcnt(0)" ::: "memory");
    }
    __builtin_amdgcn_s_barrier();

    // biases (row 80 of each tensor tile)
    float bs0[5], bs1[5];
#pragma unroll
    for (int n = 0; n < 5; ++n) {
      int s = n * 16 + lrow;
      bs0[n] = bf2f(wlds[cur][0 * WTEN + 80 * WST + s]);
      bs1[n] = bf2f(wlds[cur][1 * WTEN + 80 * WST + s]);
    }

#pragma unroll
    for (int m = 0; m < 2; ++m) {
      f32x4 y0[5], y1[5];
#pragma unroll
      for (int n = 0; n < 5; ++n) { y0[n] = 0.f; y1[n] = 0.f; }
#pragma unroll
      for (int kf = 0; kf < 3; ++kf) {
        int colb = kf * 32 + lj * 8;
        bool bvalid = colb < WST;     // kf=2,lj=3 -> col 88..95 -> wraps, mask
        int cb = bvalid ? colb : 0;
#pragma unroll
        for (int n = 0; n < 5; ++n) {
          int t = n * 16 + lrow;
          bf16x8 b0 = *(const bf16x8*)&wlds[cur][0 * WTEN + t * WST + cb];
          bf16x8 b1 = *(const bf16x8*)&wlds[cur][1 * WTEN + t * WST + cb];
          if (!bvalid) { b0 = bzero; b1 = bzero; }
          y0[n] = __builtin_amdgcn_mfma_f32_16x16x32_bf16(a0[m][kf], b0, y0[n], 0, 0, 0);
          y1[n] = __builtin_amdgcn_mfma_f32_16x16x32_bf16(a1[m][kf], b1, y1[n], 0, 0, 0);
        }
      }
#pragma unroll
      for (int n = 0; n < 5; ++n)
#pragma unroll
        for (int j = 0; j < 4; ++j)
          zacc[m][n][j] += (y0[n][j] + bs0[n]) * (y1[n][j] + bs1[n]);
    }
    __builtin_amdgcn_s_barrier();  // all waves done reading wlds[cur] before next overwrite
  }

  // signed sqrt + per-row L2 norm over the 80 chunk cols, write bf16
#pragma unroll
  for (int m = 0; m < 2; ++m) {
    float g[5][4];
    float ssj[4] = {0.f, 0.f, 0.f, 0.f};
#pragma unroll
    for (int n = 0; n < 5; ++n)
#pragma unroll
      for (int j = 0; j < 4; ++j) {
        float v = zacc[m][n][j];
        float a = sqrtf(fabsf(v));
        float gv = v < 0.f ? -a : a;
        g[n][j] = gv;
        ssj[j] += gv * gv;
      }
#pragma unroll
    for (int j = 0; j < 4; ++j) {
      float s = ssj[j];
      s += __shfl_xor(s, 1);
      s += __shfl_xor(s, 2);
      s += __shfl_xor(s, 4);
      s += __shfl_xor(s, 8);
      float nrm = sqrtf(s);
      nrm = nrm > 1e-12f ? nrm : 1e-12f;
      ssj[j] = 1.f / nrm;
    }
#pragma unroll
    for (int n = 0; n < 5; ++n) {
      int scol = n * 16 + lrow;
#pragma unroll
      for (int j = 0; j < 4; ++j) {
        int row = bt * 128 + wave * 32 + m * 16 + lj * 4 + j;
        zb[(size_t)row * MM + c * CSIZE + scol] = f2bf(g[n][j] * ssj[j]);
      }
    }
  }
}

// ---------- workspace layout (bytes) ----------
#define OFF_XB0   ((size_t)0)
#define OFF_XB1   (OFF_XB0 + (size_t)BATCH * D0D1 * 2)
#define OFF_WB0   (OFF_XB1 + (size_t)BATCH * D0D1 * 2)
#define OFF_WB1   (OFF_WB0 + (size_t)MM * D0D1 * 2)
#define OFF_WOUTB (OFF_WB1 + (size_t)MM * D0D1 * 2)
#define OFF_HB0   (OFF_WOUTB + (size_t)NOUT * MM * 2)
#define OFF_HB1   (OFF_HB0 + (size_t)BATCH * MM * 2)
#define OFF_ZB    (OFF_HB1 + (size_t)BATCH * MM * 2)
#define WS_NEED   (OFF_ZB + (size_t)BATCH * MM * 2)
// mWP (8.55 MB) aliases xb0 (16.78 MB): packed AFTER gemm_dual has consumed xb0.
#define OFF_MWP   OFF_XB0

extern "C" void kernel_launch(void* const* d_in, const int* in_sizes, int n_in,
                              void* d_out, int out_size, void* d_ws, size_t ws_size,
                              hipStream_t stream) {
  const float* x0   = (const float*)d_in[0];
  const float* x1   = (const float*)d_in[1];
  const float* W0   = (const float*)d_in[2];
  const float* b0   = (const float*)d_in[3];
  const float* W1   = (const float*)d_in[4];
  const float* b1   = (const float*)d_in[5];
  const float* mW0  = (const float*)d_in[6];
  const float* mb0  = (const float*)d_in[7];
  const float* mW1  = (const float*)d_in[8];
  const float* mb1  = (const float*)d_in[9];
  const float* Wout = (const float*)d_in[10];
  const float* bout = (const float*)d_in[11];

  if (ws_size < WS_NEED) return;

  char* ws = (char*)d_ws;
  unsigned short* xb0   = (unsigned short*)(ws + OFF_XB0);
  unsigned short* xb1   = (unsigned short*)(ws + OFF_XB1);
  unsigned short* Wb0   = (unsigned short*)(ws + OFF_WB0);
  unsigned short* Wb1   = (unsigned short*)(ws + OFF_WB1);
  unsigned short* Woutb = (unsigned short*)(ws + OFF_WOUTB);
  unsigned short* hb0   = (unsigned short*)(ws + OFF_HB0);
  unsigned short* hb1   = (unsigned short*)(ws + OFF_HB1);
  unsigned short* zb    = (unsigned short*)(ws + OFF_ZB);
  unsigned short* mWP   = (unsigned short*)(ws + OFF_MWP);

  auto cast = [&](const float* s, unsigned short* d, int n) {
    int blocks = (n / 8 + 255) / 256;
    hipLaunchKernelGGL(cast_bf16_k, dim3(blocks), dim3(256), 0, stream, s, d, n);
  };
  cast(x0, xb0, BATCH * D0D1);
  cast(x1, xb1, BATCH * D0D1);
  cast(W0, Wb0, MM * D0D1);
  cast(W1, Wb1, MM * D0D1);
  cast(Wout, Woutb, NOUT * MM);

  // stage 1: h0,h1 = x@W^T + b  -> bf16 [4096][1600]
  hipLaunchKernelGGL(gemm_dual_bf16, dim3(13, 32, 2), dim3(256), 0, stream,
                     xb0, Wb0, b0, hb0, xb1, Wb1, b1, hb1, BATCH, MM, D0D1);

  // pack mW+mb into conflict-free padded layout (into xb0's space, now free)
  hipLaunchKernelGGL(cast_mwp_k, dim3((WCH + 255) / 256, RANK, NCHUNKS), dim3(256), 0, stream,
                     mW0, mb0, mW1, mb1, mWP);

  // stage 2: chunk MM + bilinear + signed sqrt + L2 norm -> zb bf16
  hipLaunchKernelGGL(chunk_fuse2, dim3(NCHUNKS, BATCH / 128), dim3(256), 0, stream,
                     hb0, hb1, mWP, zb);

  // stage 3: out = zn@Wout^T + bout -> f32 [4096][3000]
  hipLaunchKernelGGL(gemm_f32out, dim3(24, 32), dim3(256), 0, stream,
                     zb, Woutb, bout, (float*)d_out, BATCH, NOUT, MM);
}

// Round 3
// 236.794 us; speedup vs baseline: 1.4196x; 1.1604x over previous
//
#include <hip/hip_runtime.h>

typedef unsigned int uint32;
typedef __bf16 bf16x8 __attribute__((ext_vector_type(8)));
typedef float f32x4 __attribute__((ext_vector_type(4)));

typedef __attribute__((address_space(1))) unsigned int as1_uint;
typedef __attribute__((address_space(3))) unsigned int as3_uint;

// ---------- constants ----------
#define BATCH 4096
#define D0D1 2048
#define MM 1600
#define NCHUNKS 20
#define RANK 15
#define CSIZE 80
#define TDIM 1200   // SIZE*RANK
#define NOUT 3000

// packed weight layout for stage 2 (unchanged from round 2)
#define WST 88
#define WTROWS 81
#define WTEN (WTROWS * WST)
#define WRANK (2 * WTEN)
#define WCH (WRANK * 2 / 16)

__device__ __forceinline__ unsigned short f2bf(float f) {
  unsigned int u = __builtin_bit_cast(unsigned int, f);
  u = (u + 0x7fffu + ((u >> 16) & 1u)) >> 16;
  return (unsigned short)u;
}
__device__ __forceinline__ float bf2f(unsigned short u) {
  return __builtin_bit_cast(float, (uint32)u << 16);
}

__device__ __forceinline__ void gload_lds16(const void* g, void* lds) {
  __builtin_amdgcn_global_load_lds((as1_uint*)g, (as3_uint*)lds, 16, 0, 0);
}

template <int N>
__device__ __forceinline__ void wait_vmcnt() {
  asm volatile("s_waitcnt vmcnt(%0)" :: "n"(N) : "memory");
}
__device__ __forceinline__ void barrier_mem() {
  asm volatile("s_barrier" ::: "memory");
}

// ---------- cast f32 -> bf16, 8 elems/thread ----------
__global__ __launch_bounds__(256) void cast_bf16_k(const float* __restrict__ src,
                                                   unsigned short* __restrict__ dst, int n) {
  int i = (blockIdx.x * 256 + threadIdx.x) * 8;
  if (i >= n) return;
  float4 v0 = *(const float4*)(src + i);
  float4 v1 = *(const float4*)(src + i + 4);
  uint4 o;
  o.x = (uint32)f2bf(v0.x) | ((uint32)f2bf(v0.y) << 16);
  o.y = (uint32)f2bf(v0.z) | ((uint32)f2bf(v0.w) << 16);
  o.z = (uint32)f2bf(v1.x) | ((uint32)f2bf(v1.y) << 16);
  o.w = (uint32)f2bf(v1.z) | ((uint32)f2bf(v1.w) << 16);
  *(uint4*)(dst + i) = o;
}

// ---------- pack mW + mb into padded conflict-free layout (unchanged) ----------
__global__ __launch_bounds__(256) void cast_mwp_k(
    const float* __restrict__ mW0, const float* __restrict__ mb0,
    const float* __restrict__ mW1, const float* __restrict__ mb1,
    unsigned short* __restrict__ mWP) {
  const int c = blockIdx.z, r = blockIdx.y;
  int i = blockIdx.x * 256 + threadIdx.x;
  if (i >= WCH) return;
  int e = i * 8;
  int tensor = e / WTEN;
  int rem = e - tensor * WTEN;
  int row = rem / WST;
  int col0 = rem - row * WST;

  float v[8];
  if (col0 >= CSIZE) {
#pragma unroll
    for (int k = 0; k < 8; ++k) v[k] = 0.f;
  } else if (row < CSIZE) {
    const float* src = (tensor ? mW1 : mW0) +
                       ((size_t)c * TDIM + (size_t)r * CSIZE + row) * CSIZE + col0;
#pragma unroll
    for (int k = 0; k < 8; ++k) v[k] = src[k];
  } else {
    const float* src = (tensor ? mb1 : mb0) + (size_t)c * TDIM + (size_t)r * CSIZE + col0;
#pragma unroll
    for (int k = 0; k < 8; ++k) v[k] = src[k];
  }
  uint4 o;
  o.x = (uint32)f2bf(v[0]) | ((uint32)f2bf(v[1]) << 16);
  o.y = (uint32)f2bf(v[2]) | ((uint32)f2bf(v[3]) << 16);
  o.z = (uint32)f2bf(v[4]) | ((uint32)f2bf(v[5]) << 16);
  o.w = (uint32)f2bf(v[6]) | ((uint32)f2bf(v[7]) << 16);
  *(uint4*)(mWP + ((size_t)(c * RANK + r)) * WRANK + e) = o;
}

// ---------- NT GEMM core v2: pipelined + swizzled ----------
// 128x128 tile, BK=32, 4 waves (2Mx2N, 64x64 each). 3 LDS buffers (48KB),
// stage 2 K-tiles ahead, counted vmcnt(8) (drain only in 2-iter tail).
// LDS granule swizzle: granule(r,kg) = 4r + (kg ^ ((r>>1)&3)); staging reads the
// inverse-permuted global address per lane (linear LDS dst), reads use the
// swizzled offset -> frag reads spread uniformly over all 8 bank groups.
template <bool BF16OUT>
__device__ __forceinline__ void gemm_core(const unsigned short* __restrict__ A,
                                          const unsigned short* __restrict__ B,
                                          const float* __restrict__ bias,
                                          void* __restrict__ Cv,
                                          char* lds, int M, int N, int K,
                                          int bm0, int bn0) {
  const int tid = threadIdx.x;
  const int wave = tid >> 6, lane = tid & 63;
  const int wr = (wave >> 1) * 64, wc = (wave & 1) * 64;
  const int lrow = lane & 15, lkg = lane >> 4;

  // staging source element-offsets (2 granule-blocks each for A and B)
  size_t eA[2], eB[2];
#pragma unroll
  for (int q = 0; q < 2; ++q) {
    int g = q * 256 + tid;               // granule index 0..511
    int rr = g >> 2;
    int kg = (g & 3) ^ ((rr >> 1) & 3);  // inverse swizzle on the source side
    eA[q] = (size_t)(bm0 + rr) * K + kg * 8;
    int brow = bn0 + rr;
    if (brow > N - 1) brow = N - 1;      // clamp keeps ragged-N loads in-bounds
    eB[q] = (size_t)brow * K + kg * 8;
  }
  // swizzled ds_read byte offsets
  int offA[4], offB[4];
#pragma unroll
  for (int f = 0; f < 4; ++f) {
    int ra = wr + f * 16 + lrow;
    offA[f] = (ra * 4 + (lkg ^ ((ra >> 1) & 3))) * 16;
    int rb = wc + f * 16 + lrow;
    offB[f] = (rb * 4 + (lkg ^ ((rb >> 1) & 3))) * 16;
  }

  f32x4 acc[4][4];
#pragma unroll
  for (int m = 0; m < 4; ++m)
#pragma unroll
    for (int n = 0; n < 4; ++n) acc[m][n] = 0.f;

  auto STAGE = [&](int t, int buf) {
    char* base = lds + buf * 16384;
    const unsigned short* Ak = A + (size_t)t * 32;
    const unsigned short* Bk = B + (size_t)t * 32;
#pragma unroll
    for (int q = 0; q < 2; ++q)
      gload_lds16(Ak + eA[q], base + q * 4096 + wave * 1024);
#pragma unroll
    for (int q = 0; q < 2; ++q)
      gload_lds16(Bk + eB[q], base + 8192 + q * 4096 + wave * 1024);
  };
  auto COMPUTE = [&](int buf) {
    char* base = lds + buf * 16384;
    bf16x8 a[4], b[4];
#pragma unroll
    for (int f = 0; f < 4; ++f) a[f] = *(const bf16x8*)(base + offA[f]);
#pragma unroll
    for (int f = 0; f < 4; ++f) b[f] = *(const bf16x8*)(base + 8192 + offB[f]);
    __builtin_amdgcn_s_setprio(1);
#pragma unroll
    for (int m = 0; m < 4; ++m)
#pragma unroll
      for (int n = 0; n < 4; ++n)
        acc[m][n] = __builtin_amdgcn_mfma_f32_16x16x32_bf16(a[m], b[n], acc[m][n], 0, 0, 0);
    __builtin_amdgcn_s_setprio(0);
  };

  const int nt = K >> 5;   // 64 (stage1) / 50 (stage3)
  STAGE(0, 0);
  STAGE(1, 1);
  int buf = 0;
  for (int t = 0; t < nt - 2; ++t) {
    int sb = buf + 2; if (sb >= 3) sb -= 3;
    STAGE(t + 2, sb);
    wait_vmcnt<8>();          // tile t fully landed; tiles t+1,t+2 in flight
    barrier_mem();
    COMPUTE(buf);
    barrier_mem();            // all waves done reading buf before it's restaged
    if (++buf == 3) buf = 0;
  }
  wait_vmcnt<4>();
  barrier_mem();
  COMPUTE(buf);
  barrier_mem();
  if (++buf == 3) buf = 0;
  wait_vmcnt<0>();
  barrier_mem();
  COMPUTE(buf);

  // epilogue: C/D layout col=lane&15, row=(lane>>4)*4+j
#pragma unroll
  for (int n = 0; n < 4; ++n) {
    int col = bn0 + wc + n * 16 + lrow;
    if (col < N) {
      float bv = bias[col];
#pragma unroll
      for (int m = 0; m < 4; ++m) {
#pragma unroll
        for (int j = 0; j < 4; ++j) {
          int row = bm0 + wr + m * 16 + (lane >> 4) * 4 + j;
          float v = acc[m][n][j] + bv;
          if (BF16OUT)
            ((unsigned short*)Cv)[(size_t)row * N + col] = f2bf(v);
          else
            ((float*)Cv)[(size_t)row * N + col] = v;
        }
      }
    }
  }
}

// stage-1 dual GEMM: 1-D grid 832 = 13(N) x 32(M) x 2(tensor), XCD-swizzled
__global__ __launch_bounds__(256, 3) void gemm_dual_bf16(
    const unsigned short* A0, const unsigned short* B0, const float* bias0, unsigned short* C0,
    const unsigned short* A1, const unsigned short* B1, const float* bias1, unsigned short* C1) {
  __shared__ char lds[49152];
  int orig = blockIdx.x;
  int wg = (orig & 7) * 104 + (orig >> 3);   // 832/8 = 104, bijective
  int bx = wg % 13;
  int rest = wg / 13;
  int by = rest & 31, bz = rest >> 5;
  const unsigned short* A = bz ? A1 : A0;
  const unsigned short* B = bz ? B1 : B0;
  const float* bias = bz ? bias1 : bias0;
  unsigned short* C = bz ? C1 : C0;
  gemm_core<true>(A, B, bias, C, lds, BATCH, MM, D0D1, by * 128, bx * 128);
}

// stage-3 GEMM: 1-D grid 768 = 24(N) x 32(M), XCD-swizzled
__global__ __launch_bounds__(256, 3) void gemm_f32out(
    const unsigned short* A, const unsigned short* B, const float* bias, float* C) {
  __shared__ char lds[49152];
  int orig = blockIdx.x;
  int wg = (orig & 7) * 96 + (orig >> 3);    // 768/8 = 96, bijective
  int bx = wg % 24;
  int by = wg / 24;
  gemm_core<false>(A, B, bias, C, lds, BATCH, NOUT, MM, by * 128, bx * 128);
}

// ---------- stage 2: h in registers, async double-buffered weight staging ----------
__global__ __launch_bounds__(256, 2) void chunk_fuse2(
    const unsigned short* __restrict__ hb0, const unsigned short* __restrict__ hb1,
    const unsigned short* __restrict__ mWP, unsigned short* __restrict__ zb) {
  const int c = blockIdx.x, bt = blockIdx.y;
  __shared__ unsigned short wlds[2][WRANK];
  const int tid = threadIdx.x, wave = tid >> 6, lane = tid & 63;
  const int lrow = lane & 15, lj = lane >> 4;

  bf16x8 bzero;
  bzero = (__bf16)0.0f;

  bf16x8 a0[2][3], a1[2][3];
#pragma unroll
  for (int m = 0; m < 2; ++m)
#pragma unroll
    for (int kf = 0; kf < 3; ++kf) {
      int col = kf * 32 + lj * 8;
      bool valid = col < CSIZE;
      int row = bt * 128 + wave * 32 + m * 16 + lrow;
      size_t base = (size_t)row * MM + c * CSIZE + (valid ? col : 0);
      bf16x8 v0 = *(const bf16x8*)(hb0 + base);
      bf16x8 v1 = *(const bf16x8*)(hb1 + base);
      a0[m][kf] = valid ? v0 : bzero;
      a1[m][kf] = valid ? v1 : bzero;
    }

  const unsigned short* wsrc = mWP + (size_t)(c * RANK) * WRANK;
  auto STAGE = [&](int buf, int r) {
    const unsigned short* src = wsrc + (size_t)r * WRANK;
    char* dstb = (char*)&wlds[buf][0];
#pragma unroll
    for (int k = 0; k < 7; ++k) {
      int i = k * 256 + tid;
      if (i < WCH)
        gload_lds16(src + (size_t)i * 8, dstb + (k * 256 + wave * 64) * 16);
    }
  };

  f32x4 zacc[2][5];
#pragma unroll
  for (int m = 0; m < 2; ++m)
#pragma unroll
    for (int n = 0; n < 5; ++n) zacc[m][n] = 0.f;

  STAGE(0, 0);
  for (int r = 0; r < RANK; ++r) {
    int cur = r & 1;
    if (r < RANK - 1) {
      STAGE(cur ^ 1, r + 1);
      asm volatile("s_waitcnt vmcnt(7)" ::: "memory");
    } else {
      asm volatile("s_waitcnt vmcnt(0)" ::: "memory");
    }
    __builtin_amdgcn_s_barrier();

    float bs0[5], bs1[5];
#pragma unroll
    for (int n = 0; n < 5; ++n) {
      int s = n * 16 + lrow;
      bs0[n] = bf2f(wlds[cur][0 * WTEN + 80 * WST + s]);
      bs1[n] = bf2f(wlds[cur][1 * WTEN + 80 * WST + s]);
    }

#pragma unroll
    for (int m = 0; m < 2; ++m) {
      f32x4 y0[5], y1[5];
#pragma unroll
      for (int n = 0; n < 5; ++n) { y0[n] = 0.f; y1[n] = 0.f; }
#pragma unroll
      for (int kf = 0; kf < 3; ++kf) {
        int colb = kf * 32 + lj * 8;
        bool bvalid = colb < WST;
        int cb = bvalid ? colb : 0;
#pragma unroll
        for (int n = 0; n < 5; ++n) {
          int t = n * 16 + lrow;
          bf16x8 b0 = *(const bf16x8*)&wlds[cur][0 * WTEN + t * WST + cb];
          bf16x8 b1 = *(const bf16x8*)&wlds[cur][1 * WTEN + t * WST + cb];
          if (!bvalid) { b0 = bzero; b1 = bzero; }
          y0[n] = __builtin_amdgcn_mfma_f32_16x16x32_bf16(a0[m][kf], b0, y0[n], 0, 0, 0);
          y1[n] = __builtin_amdgcn_mfma_f32_16x16x32_bf16(a1[m][kf], b1, y1[n], 0, 0, 0);
        }
      }
#pragma unroll
      for (int n = 0; n < 5; ++n)
#pragma unroll
        for (int j = 0; j < 4; ++j)
          zacc[m][n][j] += (y0[n][j] + bs0[n]) * (y1[n][j] + bs1[n]);
    }
    __builtin_amdgcn_s_barrier();
  }

#pragma unroll
  for (int m = 0; m < 2; ++m) {
    float g[5][4];
    float ssj[4] = {0.f, 0.f, 0.f, 0.f};
#pragma unroll
    for (int n = 0; n < 5; ++n)
#pragma unroll
      for (int j = 0; j < 4; ++j) {
        float v = zacc[m][n][j];
        float a = sqrtf(fabsf(v));
        float gv = v < 0.f ? -a : a;
        g[n][j] = gv;
        ssj[j] += gv * gv;
      }
#pragma unroll
    for (int j = 0; j < 4; ++j) {
      float s = ssj[j];
      s += __shfl_xor(s, 1);
      s += __shfl_xor(s, 2);
      s += __shfl_xor(s, 4);
      s += __shfl_xor(s, 8);
      float nrm = sqrtf(s);
      nrm = nrm > 1e-12f ? nrm : 1e-12f;
      ssj[j] = 1.f / nrm;
    }
#pragma unroll
    for (int n = 0; n < 5; ++n) {
      int scol = n * 16 + lrow;
#pragma unroll
      for (int j = 0; j < 4; ++j) {
        int row = bt * 128 + wave * 32 + m * 16 + lj * 4 + j;
        zb[(size_t)row * MM + c * CSIZE + scol] = f2bf(g[n][j] * ssj[j]);
      }
    }
  }
}

// ---------- workspace layout (bytes) ----------
#define OFF_XB0   ((size_t)0)
#define OFF_XB1   (OFF_XB0 + (size_t)BATCH * D0D1 * 2)
#define OFF_WB0   (OFF_XB1 + (size_t)BATCH * D0D1 * 2)
#define OFF_WB1   (OFF_WB0 + (size_t)MM * D0D1 * 2)
#define OFF_WOUTB (OFF_WB1 + (size_t)MM * D0D1 * 2)
#define OFF_HB0   (OFF_WOUTB + (size_t)NOUT * MM * 2)
#define OFF_HB1   (OFF_HB0 + (size_t)BATCH * MM * 2)
#define OFF_ZB    (OFF_HB1 + (size_t)BATCH * MM * 2)
#define WS_NEED   (OFF_ZB + (size_t)BATCH * MM * 2)
#define OFF_MWP   OFF_XB0   // mWP aliases xb0, packed after gemm_dual consumed it

extern "C" void kernel_launch(void* const* d_in, const int* in_sizes, int n_in,
                              void* d_out, int out_size, void* d_ws, size_t ws_size,
                              hipStream_t stream) {
  const float* x0   = (const float*)d_in[0];
  const float* x1   = (const float*)d_in[1];
  const float* W0   = (const float*)d_in[2];
  const float* b0   = (const float*)d_in[3];
  const float* W1   = (const float*)d_in[4];
  const float* b1   = (const float*)d_in[5];
  const float* mW0  = (const float*)d_in[6];
  const float* mb0  = (const float*)d_in[7];
  const float* mW1  = (const float*)d_in[8];
  const float* mb1  = (const float*)d_in[9];
  const float* Wout = (const float*)d_in[10];
  const float* bout = (const float*)d_in[11];

  if (ws_size < WS_NEED) return;

  char* ws = (char*)d_ws;
  unsigned short* xb0   = (unsigned short*)(ws + OFF_XB0);
  unsigned short* xb1   = (unsigned short*)(ws + OFF_XB1);
  unsigned short* Wb0   = (unsigned short*)(ws + OFF_WB0);
  unsigned short* Wb1   = (unsigned short*)(ws + OFF_WB1);
  unsigned short* Woutb = (unsigned short*)(ws + OFF_WOUTB);
  unsigned short* hb0   = (unsigned short*)(ws + OFF_HB0);
  unsigned short* hb1   = (unsigned short*)(ws + OFF_HB1);
  unsigned short* zb    = (unsigned short*)(ws + OFF_ZB);
  unsigned short* mWP   = (unsigned short*)(ws + OFF_MWP);

  auto cast = [&](const float* s, unsigned short* d, int n) {
    int blocks = (n / 8 + 255) / 256;
    hipLaunchKernelGGL(cast_bf16_k, dim3(blocks), dim3(256), 0, stream, s, d, n);
  };
  cast(x0, xb0, BATCH * D0D1);
  cast(x1, xb1, BATCH * D0D1);
  cast(W0, Wb0, MM * D0D1);
  cast(W1, Wb1, MM * D0D1);
  cast(Wout, Woutb, NOUT * MM);

  // stage 1: h0,h1 = x@W^T + b  -> bf16 [4096][1600]
  hipLaunchKernelGGL(gemm_dual_bf16, dim3(832), dim3(256), 0, stream,
                     xb0, Wb0, b0, hb0, xb1, Wb1, b1, hb1);

  // pack mW+mb (into xb0's space, now free)
  hipLaunchKernelGGL(cast_mwp_k, dim3((WCH + 255) / 256, RANK, NCHUNKS), dim3(256), 0, stream,
                     mW0, mb0, mW1, mb1, mWP);

  // stage 2: chunk MM + bilinear + signed sqrt + L2 norm -> zb bf16
  hipLaunchKernelGGL(chunk_fuse2, dim3(NCHUNKS, BATCH / 128), dim3(256), 0, stream,
                     hb0, hb1, mWP, zb);

  // stage 3: out = zn@Wout^T + bout -> f32 [4096][3000]
  hipLaunchKernelGGL(gemm_f32out, dim3(768), dim3(256), 0, stream,
                     zb, Woutb, bout, (float*)d_out);
}

// Round 4
// 231.924 us; speedup vs baseline: 1.4494x; 1.0210x over previous
//
#include <hip/hip_runtime.h>

typedef unsigned int uint32;
typedef __bf16 bf16x8 __attribute__((ext_vector_type(8)));
typedef float f32x4 __attribute__((ext_vector_type(4)));

typedef __attribute__((address_space(1))) unsigned int as1_uint;
typedef __attribute__((address_space(3))) unsigned int as3_uint;

// ---------- constants ----------
#define BATCH 4096
#define D0D1 2048
#define MM 1600
#define NCHUNKS 20
#define RANK 15
#define CSIZE 80
#define TDIM 1200   // SIZE*RANK
#define NOUT 3000

// packed weight layout for stage 2 (unchanged)
#define WST 88
#define WTROWS 81
#define WTEN (WTROWS * WST)
#define WRANK (2 * WTEN)
#define WCH (WRANK * 2 / 16)

__device__ __forceinline__ unsigned short f2bf(float f) {
  unsigned int u = __builtin_bit_cast(unsigned int, f);
  u = (u + 0x7fffu + ((u >> 16) & 1u)) >> 16;
  return (unsigned short)u;
}
__device__ __forceinline__ float bf2f(unsigned short u) {
  return __builtin_bit_cast(float, (uint32)u << 16);
}

__device__ __forceinline__ void gload_lds16(const void* g, void* lds) {
  __builtin_amdgcn_global_load_lds((as1_uint*)g, (as3_uint*)lds, 16, 0, 0);
}

template <int N>
__device__ __forceinline__ void wait_vmcnt() {
  asm volatile("s_waitcnt vmcnt(%0)" :: "n"(N) : "memory");
}
__device__ __forceinline__ void barrier_mem() {
  asm volatile("s_barrier" ::: "memory");
}

// ---------- cast f32 -> bf16, 8 elems/thread ----------
__global__ __launch_bounds__(256) void cast_bf16_k(const float* __restrict__ src,
                                                   unsigned short* __restrict__ dst, int n) {
  int i = (blockIdx.x * 256 + threadIdx.x) * 8;
  if (i >= n) return;
  float4 v0 = *(const float4*)(src + i);
  float4 v1 = *(const float4*)(src + i + 4);
  uint4 o;
  o.x = (uint32)f2bf(v0.x) | ((uint32)f2bf(v0.y) << 16);
  o.y = (uint32)f2bf(v0.z) | ((uint32)f2bf(v0.w) << 16);
  o.z = (uint32)f2bf(v1.x) | ((uint32)f2bf(v1.y) << 16);
  o.w = (uint32)f2bf(v1.z) | ((uint32)f2bf(v1.w) << 16);
  *(uint4*)(dst + i) = o;
}

// ---------- pack mW + mb into padded conflict-free layout (unchanged) ----------
__global__ __launch_bounds__(256) void cast_mwp_k(
    const float* __restrict__ mW0, const float* __restrict__ mb0,
    const float* __restrict__ mW1, const float* __restrict__ mb1,
    unsigned short* __restrict__ mWP) {
  const int c = blockIdx.z, r = blockIdx.y;
  int i = blockIdx.x * 256 + threadIdx.x;
  if (i >= WCH) return;
  int e = i * 8;
  int tensor = e / WTEN;
  int rem = e - tensor * WTEN;
  int row = rem / WST;
  int col0 = rem - row * WST;

  float v[8];
  if (col0 >= CSIZE) {
#pragma unroll
    for (int k = 0; k < 8; ++k) v[k] = 0.f;
  } else if (row < CSIZE) {
    const float* src = (tensor ? mW1 : mW0) +
                       ((size_t)c * TDIM + (size_t)r * CSIZE + row) * CSIZE + col0;
#pragma unroll
    for (int k = 0; k < 8; ++k) v[k] = src[k];
  } else {
    const float* src = (tensor ? mb1 : mb0) + (size_t)c * TDIM + (size_t)r * CSIZE + col0;
#pragma unroll
    for (int k = 0; k < 8; ++k) v[k] = src[k];
  }
  uint4 o;
  o.x = (uint32)f2bf(v[0]) | ((uint32)f2bf(v[1]) << 16);
  o.y = (uint32)f2bf(v[2]) | ((uint32)f2bf(v[3]) << 16);
  o.z = (uint32)f2bf(v[4]) | ((uint32)f2bf(v[5]) << 16);
  o.w = (uint32)f2bf(v[6]) | ((uint32)f2bf(v[7]) << 16);
  *(uint4*)(mWP + ((size_t)(c * RANK + r)) * WRANK + e) = o;
}

// ---------- NT GEMM core v3: 256x256 tile, BK=32, 8 waves, 4-buffer ring ----------
// Wave grid 2(M)x4(N): wave (wm,wn) owns a 128x64 C-block = 8x4 16x16 frags.
// LDS per buffer: A 256x32 (16KB, granule-swizzled) + B 256x32 (16KB); 4 bufs = 128KB.
// granule(r,kg) = r*4 + (kg ^ ((r>>1)&3)) -> measured conflict-free (round 3).
// Prefetch 3 tiles ahead, counted vmcnt(12); restage of buf happens one iter after
// its compute, made safe by the trailing barrier (reads completed before it).
template <bool BF16OUT>
__device__ __forceinline__ void gemm256_core(const unsigned short* __restrict__ A,
                                             const unsigned short* __restrict__ B,
                                             const float* __restrict__ bias,
                                             void* __restrict__ Cv,
                                             char* lds, int N, int K,
                                             int bm0, int bn0) {
  const int tid = threadIdx.x;
  const int wave = tid >> 6, lane = tid & 63;
  const int wm = wave >> 2, wn = wave & 3;       // 2 x 4 wave grid
  const int lrow = lane & 15, lj = lane >> 4;

  // staging source byte-offsets: 2 granule-sets each for A and B
  uint32 eA[2], eB[2];
#pragma unroll
  for (int q = 0; q < 2; ++q) {
    int g = q * 512 + wave * 64 + lane;          // granule 0..1023
    int row = g >> 2;
    int kg = (g & 3) ^ ((row >> 1) & 3);         // inverse swizzle on source side
    eA[q] = (uint32)((bm0 + row) * K + kg * 8) * 2;
    int brow = bn0 + row;
    if (brow > N - 1) brow = N - 1;              // clamp keeps ragged-N loads in-bounds
    eB[q] = (uint32)(brow * K + kg * 8) * 2;
  }
  // swizzled ds_read byte offsets (A: 8 frags, B: 4 frags)
  int offA[8], offB[4];
#pragma unroll
  for (int m = 0; m < 8; ++m) {
    int r = wm * 128 + m * 16 + lrow;
    offA[m] = (r * 4 + (lj ^ ((r >> 1) & 3))) * 16;
  }
#pragma unroll
  for (int n = 0; n < 4; ++n) {
    int r = wn * 64 + n * 16 + lrow;
    offB[n] = (r * 4 + (lj ^ ((r >> 1) & 3))) * 16;
  }

  f32x4 acc[8][4];
#pragma unroll
  for (int m = 0; m < 8; ++m)
#pragma unroll
    for (int n = 0; n < 4; ++n) acc[m][n] = 0.f;

  const char* Ab = (const char*)A;
  const char* Bb = (const char*)B;
  auto STAGE = [&](int t, int buf) {
    uint32 kbyte = (uint32)t * 64;
    char* base = lds + buf * 32768;
#pragma unroll
    for (int q = 0; q < 2; ++q)
      gload_lds16(Ab + eA[q] + kbyte, base + (q * 512 + wave * 64) * 16);
#pragma unroll
    for (int q = 0; q < 2; ++q)
      gload_lds16(Bb + eB[q] + kbyte, base + 16384 + (q * 512 + wave * 64) * 16);
  };
  auto COMPUTE = [&](int buf) {
    char* base = lds + buf * 32768;
    bf16x8 b[4];
#pragma unroll
    for (int n = 0; n < 4; ++n) b[n] = *(const bf16x8*)(base + 16384 + offB[n]);
    bf16x8 a[8];
#pragma unroll
    for (int m = 0; m < 8; ++m) a[m] = *(const bf16x8*)(base + offA[m]);
    __builtin_amdgcn_s_setprio(1);
#pragma unroll
    for (int m = 0; m < 8; ++m)
#pragma unroll
      for (int n = 0; n < 4; ++n)
        acc[m][n] = __builtin_amdgcn_mfma_f32_16x16x32_bf16(a[m], b[n], acc[m][n], 0, 0, 0);
    __builtin_amdgcn_s_setprio(0);
  };

  const int nt = K >> 5;        // 64 (stage 1) / 50 (stage 3)
  STAGE(0, 0);
  STAGE(1, 1);
  STAGE(2, 2);
  int buf = 0;
  for (int t = 0; t < nt - 3; ++t) {
    STAGE(t + 3, (t + 3) & 3);
    wait_vmcnt<12>();           // tile t landed; t+1..t+3 in flight
    barrier_mem();
    COMPUTE(buf);
    barrier_mem();              // all reads of buf done before its restage next iter
    buf = (buf + 1) & 3;
  }
  wait_vmcnt<8>();
  barrier_mem();
  COMPUTE(buf);
  barrier_mem();
  buf = (buf + 1) & 3;
  wait_vmcnt<4>();
  barrier_mem();
  COMPUTE(buf);
  barrier_mem();
  buf = (buf + 1) & 3;
  wait_vmcnt<0>();
  barrier_mem();
  COMPUTE(buf);

  // epilogue: C/D layout col=lane&15, row=(lane>>4)*4+j
#pragma unroll
  for (int n = 0; n < 4; ++n) {
    int col = bn0 + wn * 64 + n * 16 + lrow;
    if (col < N) {
      float bv = bias[col];
#pragma unroll
      for (int m = 0; m < 8; ++m) {
#pragma unroll
        for (int j = 0; j < 4; ++j) {
          int row = bm0 + wm * 128 + m * 16 + lj * 4 + j;
          float v = acc[m][n][j] + bv;
          if (BF16OUT)
            ((unsigned short*)Cv)[(size_t)row * N + col] = f2bf(v);
          else
            ((float*)Cv)[(size_t)row * N + col] = v;
        }
      }
    }
  }
}

// stage-1 dual GEMM: grid 224 = 7(N) x 16(M) x 2(tensor), all co-resident
__global__ __launch_bounds__(512, 2) void gemm_dual_256(
    const unsigned short* A0, const unsigned short* B0, const float* bias0, unsigned short* C0,
    const unsigned short* A1, const unsigned short* B1, const float* bias1, unsigned short* C1) {
  __shared__ char lds[131072];
  int wg = blockIdx.x;
  int bx = wg % 7;
  int r = wg / 7;
  int by = r & 15, bz = r >> 4;
  const unsigned short* A = bz ? A1 : A0;
  const unsigned short* B = bz ? B1 : B0;
  const float* bias = bz ? bias1 : bias0;
  unsigned short* C = bz ? C1 : C0;
  gemm256_core<true>(A, B, bias, C, lds, MM, D0D1, by * 256, bx * 256);
}

// stage-3 GEMM: grid 192 = 12(N) x 16(M), all co-resident
__global__ __launch_bounds__(512, 2) void gemm_out_256(
    const unsigned short* A, const unsigned short* B, const float* bias, float* C) {
  __shared__ char lds[131072];
  int wg = blockIdx.x;
  int bx = wg % 12;
  int by = wg / 12;
  gemm256_core<false>(A, B, bias, C, lds, NOUT, MM, by * 256, bx * 256);
}

// ---------- stage 2: h in registers, async double-buffered weight staging ----------
__global__ __launch_bounds__(256, 2) void chunk_fuse2(
    const unsigned short* __restrict__ hb0, const unsigned short* __restrict__ hb1,
    const unsigned short* __restrict__ mWP, unsigned short* __restrict__ zb) {
  const int c = blockIdx.x, bt = blockIdx.y;
  __shared__ unsigned short wlds[2][WRANK];
  const int tid = threadIdx.x, wave = tid >> 6, lane = tid & 63;
  const int lrow = lane & 15, lj = lane >> 4;

  bf16x8 bzero;
  bzero = (__bf16)0.0f;

  bf16x8 a0[2][3], a1[2][3];
#pragma unroll
  for (int m = 0; m < 2; ++m)
#pragma unroll
    for (int kf = 0; kf < 3; ++kf) {
      int col = kf * 32 + lj * 8;
      bool valid = col < CSIZE;
      int row = bt * 128 + wave * 32 + m * 16 + lrow;
      size_t base = (size_t)row * MM + c * CSIZE + (valid ? col : 0);
      bf16x8 v0 = *(const bf16x8*)(hb0 + base);
      bf16x8 v1 = *(const bf16x8*)(hb1 + base);
      a0[m][kf] = valid ? v0 : bzero;
      a1[m][kf] = valid ? v1 : bzero;
    }

  const unsigned short* wsrc = mWP + (size_t)(c * RANK) * WRANK;
  auto STAGE = [&](int buf, int r) {
    const unsigned short* src = wsrc + (size_t)r * WRANK;
    char* dstb = (char*)&wlds[buf][0];
#pragma unroll
    for (int k = 0; k < 7; ++k) {
      int i = k * 256 + tid;
      if (i < WCH)
        gload_lds16(src + (size_t)i * 8, dstb + (k * 256 + wave * 64) * 16);
    }
  };

  f32x4 zacc[2][5];
#pragma unroll
  for (int m = 0; m < 2; ++m)
#pragma unroll
    for (int n = 0; n < 5; ++n) zacc[m][n] = 0.f;

  STAGE(0, 0);
  for (int r = 0; r < RANK; ++r) {
    int cur = r & 1;
    if (r < RANK - 1) {
      STAGE(cur ^ 1, r + 1);
      asm volatile("s_waitcnt vmcnt(7)" ::: "memory");
    } else {
      asm volatile("s_waitcnt vmcnt(0)" ::: "memory");
    }
    __builtin_amdgcn_s_barrier();

    float bs0[5], bs1[5];
#pragma unroll
    for (int n = 0; n < 5; ++n) {
      int s = n * 16 + lrow;
      bs0[n] = bf2f(wlds[cur][0 * WTEN + 80 * WST + s]);
      bs1[n] = bf2f(wlds[cur][1 * WTEN + 80 * WST + s]);
    }

#pragma unroll
    for (int m = 0; m < 2; ++m) {
      f32x4 y0[5], y1[5];
#pragma unroll
      for (int n = 0; n < 5; ++n) { y0[n] = 0.f; y1[n] = 0.f; }
#pragma unroll
      for (int kf = 0; kf < 3; ++kf) {
        int colb = kf * 32 + lj * 8;
        bool bvalid = colb < WST;
        int cb = bvalid ? colb : 0;
#pragma unroll
        for (int n = 0; n < 5; ++n) {
          int t = n * 16 + lrow;
          bf16x8 b0 = *(const bf16x8*)&wlds[cur][0 * WTEN + t * WST + cb];
          bf16x8 b1 = *(const bf16x8*)&wlds[cur][1 * WTEN + t * WST + cb];
          if (!bvalid) { b0 = bzero; b1 = bzero; }
          y0[n] = __builtin_amdgcn_mfma_f32_16x16x32_bf16(a0[m][kf], b0, y0[n], 0, 0, 0);
          y1[n] = __builtin_amdgcn_mfma_f32_16x16x32_bf16(a1[m][kf], b1, y1[n], 0, 0, 0);
        }
      }
#pragma unroll
      for (int n = 0; n < 5; ++n)
#pragma unroll
        for (int j = 0; j < 4; ++j)
          zacc[m][n][j] += (y0[n][j] + bs0[n]) * (y1[n][j] + bs1[n]);
    }
    __builtin_amdgcn_s_barrier();
  }

#pragma unroll
  for (int m = 0; m < 2; ++m) {
    float g[5][4];
    float ssj[4] = {0.f, 0.f, 0.f, 0.f};
#pragma unroll
    for (int n = 0; n < 5; ++n)
#pragma unroll
      for (int j = 0; j < 4; ++j) {
        float v = zacc[m][n][j];
        float a = sqrtf(fabsf(v));
        float gv = v < 0.f ? -a : a;
        g[n][j] = gv;
        ssj[j] += gv * gv;
      }
#pragma unroll
    for (int j = 0; j < 4; ++j) {
      float s = ssj[j];
      s += __shfl_xor(s, 1);
      s += __shfl_xor(s, 2);
      s += __shfl_xor(s, 4);
      s += __shfl_xor(s, 8);
      float nrm = sqrtf(s);
      nrm = nrm > 1e-12f ? nrm : 1e-12f;
      ssj[j] = 1.f / nrm;
    }
#pragma unroll
    for (int n = 0; n < 5; ++n) {
      int scol = n * 16 + lrow;
#pragma unroll
      for (int j = 0; j < 4; ++j) {
        int row = bt * 128 + wave * 32 + m * 16 + lj * 4 + j;
        zb[(size_t)row * MM + c * CSIZE + scol] = f2bf(g[n][j] * ssj[j]);
      }
    }
  }
}

// ---------- workspace layout (bytes) ----------
#define OFF_XB0   ((size_t)0)
#define OFF_XB1   (OFF_XB0 + (size_t)BATCH * D0D1 * 2)
#define OFF_WB0   (OFF_XB1 + (size_t)BATCH * D0D1 * 2)
#define OFF_WB1   (OFF_WB0 + (size_t)MM * D0D1 * 2)
#define OFF_WOUTB (OFF_WB1 + (size_t)MM * D0D1 * 2)
#define OFF_HB0   (OFF_WOUTB + (size_t)NOUT * MM * 2)
#define OFF_HB1   (OFF_HB0 + (size_t)BATCH * MM * 2)
#define OFF_ZB    (OFF_HB1 + (size_t)BATCH * MM * 2)
#define WS_NEED   (OFF_ZB + (size_t)BATCH * MM * 2)
#define OFF_MWP   OFF_XB0   // mWP aliases xb0, packed after gemm_dual consumed it

extern "C" void kernel_launch(void* const* d_in, const int* in_sizes, int n_in,
                              void* d_out, int out_size, void* d_ws, size_t ws_size,
                              hipStream_t stream) {
  const float* x0   = (const float*)d_in[0];
  const float* x1   = (const float*)d_in[1];
  const float* W0   = (const float*)d_in[2];
  const float* b0   = (const float*)d_in[3];
  const float* W1   = (const float*)d_in[4];
  const float* b1   = (const float*)d_in[5];
  const float* mW0  = (const float*)d_in[6];
  const float* mb0  = (const float*)d_in[7];
  const float* mW1  = (const float*)d_in[8];
  const float* mb1  = (const float*)d_in[9];
  const float* Wout = (const float*)d_in[10];
  const float* bout = (const float*)d_in[11];

  if (ws_size < WS_NEED) return;

  char* ws = (char*)d_ws;
  unsigned short* xb0   = (unsigned short*)(ws + OFF_XB0);
  unsigned short* xb1   = (unsigned short*)(ws + OFF_XB1);
  unsigned short* Wb0   = (unsigned short*)(ws + OFF_WB0);
  unsigned short* Wb1   = (unsigned short*)(ws + OFF_WB1);
  unsigned short* Woutb = (unsigned short*)(ws + OFF_WOUTB);
  unsigned short* hb0   = (unsigned short*)(ws + OFF_HB0);
  unsigned short* hb1   = (unsigned short*)(ws + OFF_HB1);
  unsigned short* zb    = (unsigned short*)(ws + OFF_ZB);
  unsigned short* mWP   = (unsigned short*)(ws + OFF_MWP);

  auto cast = [&](const float* s, unsigned short* d, int n) {
    int blocks = (n / 8 + 255) / 256;
    hipLaunchKernelGGL(cast_bf16_k, dim3(blocks), dim3(256), 0, stream, s, d, n);
  };
  cast(x0, xb0, BATCH * D0D1);
  cast(x1, xb1, BATCH * D0D1);
  cast(W0, Wb0, MM * D0D1);
  cast(W1, Wb1, MM * D0D1);
  cast(Wout, Woutb, NOUT * MM);

  // stage 1: h0,h1 = x@W^T + b  -> bf16 [4096][1600]
  hipLaunchKernelGGL(gemm_dual_256, dim3(224), dim3(512), 0, stream,
                     xb0, Wb0, b0, hb0, xb1, Wb1, b1, hb1);

  // pack mW+mb (into xb0's space, now free)
  hipLaunchKernelGGL(cast_mwp_k, dim3((WCH + 255) / 256, RANK, NCHUNKS), dim3(256), 0, stream,
                     mW0, mb0, mW1, mb1, mWP);

  // stage 2: chunk MM + bilinear + signed sqrt + L2 norm -> zb bf16
  hipLaunchKernelGGL(chunk_fuse2, dim3(NCHUNKS, BATCH / 128), dim3(256), 0, stream,
                     hb0, hb1, mWP, zb);

  // stage 3: out = zn@Wout^T + bout -> f32 [4096][3000]
  hipLaunchKernelGGL(gemm_out_256, dim3(192), dim3(512), 0, stream,
                     zb, Woutb, bout, (float*)d_out);
}

// Round 5
// 227.378 us; speedup vs baseline: 1.4784x; 1.0200x over previous
//
#include <hip/hip_runtime.h>

typedef unsigned int uint32;
typedef __bf16 bf16x8 __attribute__((ext_vector_type(8)));
typedef float f32x4 __attribute__((ext_vector_type(4)));

typedef __attribute__((address_space(1))) unsigned int as1_uint;
typedef __attribute__((address_space(3))) unsigned int as3_uint;

// ---------- constants ----------
#define BATCH 4096
#define D0D1 2048
#define MM 1600
#define NCHUNKS 20
#define RANK 15
#define CSIZE 80
#define TDIM 1200   // SIZE*RANK
#define NOUT 3000

// packed weight layout for stage 2 (unchanged)
#define WST 88
#define WTROWS 81
#define WTEN (WTROWS * WST)
#define WRANK (2 * WTEN)
#define WCH (WRANK * 2 / 16)

__device__ __forceinline__ unsigned short f2bf(float f) {
  unsigned int u = __builtin_bit_cast(unsigned int, f);
  u = (u + 0x7fffu + ((u >> 16) & 1u)) >> 16;
  return (unsigned short)u;
}
__device__ __forceinline__ float bf2f(unsigned short u) {
  return __builtin_bit_cast(float, (uint32)u << 16);
}

__device__ __forceinline__ void gload_lds16(const void* g, void* lds) {
  __builtin_amdgcn_global_load_lds((as1_uint*)g, (as3_uint*)lds, 16, 0, 0);
}

template <int N>
__device__ __forceinline__ void wait_vmcnt() {
  asm volatile("s_waitcnt vmcnt(%0)" :: "n"(N) : "memory");
}
__device__ __forceinline__ void barrier_mem() {
  asm volatile("s_barrier" ::: "memory");
}

// ---------- cast f32 -> bf16, 8 elems/thread ----------
__global__ __launch_bounds__(256) void cast_bf16_k(const float* __restrict__ src,
                                                   unsigned short* __restrict__ dst, int n) {
  int i = (blockIdx.x * 256 + threadIdx.x) * 8;
  if (i >= n) return;
  float4 v0 = *(const float4*)(src + i);
  float4 v1 = *(const float4*)(src + i + 4);
  uint4 o;
  o.x = (uint32)f2bf(v0.x) | ((uint32)f2bf(v0.y) << 16);
  o.y = (uint32)f2bf(v0.z) | ((uint32)f2bf(v0.w) << 16);
  o.z = (uint32)f2bf(v1.x) | ((uint32)f2bf(v1.y) << 16);
  o.w = (uint32)f2bf(v1.z) | ((uint32)f2bf(v1.w) << 16);
  *(uint4*)(dst + i) = o;
}

// ---------- pack mW + mb into padded conflict-free layout (unchanged) ----------
__global__ __launch_bounds__(256) void cast_mwp_k(
    const float* __restrict__ mW0, const float* __restrict__ mb0,
    const float* __restrict__ mW1, const float* __restrict__ mb1,
    unsigned short* __restrict__ mWP) {
  const int c = blockIdx.z, r = blockIdx.y;
  int i = blockIdx.x * 256 + threadIdx.x;
  if (i >= WCH) return;
  int e = i * 8;
  int tensor = e / WTEN;
  int rem = e - tensor * WTEN;
  int row = rem / WST;
  int col0 = rem - row * WST;

  float v[8];
  if (col0 >= CSIZE) {
#pragma unroll
    for (int k = 0; k < 8; ++k) v[k] = 0.f;
  } else if (row < CSIZE) {
    const float* src = (tensor ? mW1 : mW0) +
                       ((size_t)c * TDIM + (size_t)r * CSIZE + row) * CSIZE + col0;
#pragma unroll
    for (int k = 0; k < 8; ++k) v[k] = src[k];
  } else {
    const float* src = (tensor ? mb1 : mb0) + (size_t)c * TDIM + (size_t)r * CSIZE + col0;
#pragma unroll
    for (int k = 0; k < 8; ++k) v[k] = src[k];
  }
  uint4 o;
  o.x = (uint32)f2bf(v[0]) | ((uint32)f2bf(v[1]) << 16);
  o.y = (uint32)f2bf(v[2]) | ((uint32)f2bf(v[3]) << 16);
  o.z = (uint32)f2bf(v[4]) | ((uint32)f2bf(v[5]) << 16);
  o.w = (uint32)f2bf(v[6]) | ((uint32)f2bf(v[7]) << 16);
  *(uint4*)(mWP + ((size_t)(c * RANK + r)) * WRANK + e) = o;
}

// ---------- NT GEMM core v4: 256x256 tile, BK=32, phase-pipelined 16-slot ring ----------
// 8 waves (2M x 4N), wave owns 128x64 C. Half-tile = 128 rows x 32 K bf16 = 8KB;
// step t occupies slots (4t..4t+3)&15: {A rows0-127, A rows128-255, B0-127, B128-255}.
// Granule swizzle kgsw = kg ^ (row&3): staging pre-permutes the GLOBAL source per
// lane (LDS dst linear, rule 21); ds_read applies the same XOR -> bank-balanced.
// Schedule per step: 2 phases of {stage 2 halves of step t+2; vmcnt(6); s_barrier;
// ds_read (8 or 4 x b128); setprio(1); 16 MFMA; setprio(0)}. Staging runs 2 steps
// ahead (3-phase landing slack); vmcnt drains only in the 2-step tail (6->4->0).
// Restage-vs-read safety: slot rewritten >=3 phases after its last read; max wave
// skew with one barrier/phase is 1 phase.
template <bool BF16OUT>
__device__ __forceinline__ void gemm256_core(const unsigned short* __restrict__ A,
                                             const unsigned short* __restrict__ B,
                                             const float* __restrict__ bias,
                                             void* __restrict__ Cv,
                                             char* lds, int N, int K, int nt,
                                             int bm0, int bn0) {
  const int tid = threadIdx.x;
  const int wave = tid >> 6, lane = tid & 63;
  const int wm = wave >> 2, wn = wave & 3;
  const int lrow = lane & 15, lj = lane >> 4;

  // staging source byte offset per half-tile (1 granule = 16B per thread per half)
  uint32 e[4];
#pragma unroll
  for (int h = 0; h < 4; ++h) {
    int r = tid >> 2;                 // row 0..127 within half
    int kg = (tid & 3) ^ (r & 3);     // inverse swizzle on the source side
    int row = (h < 2) ? (bm0 + h * 128 + r) : (bn0 + (h - 2) * 128 + r);
    if (h >= 2 && row > N - 1) row = N - 1;   // clamp keeps ragged-N loads in-bounds
    e[h] = (uint32)(row * K + kg * 8) * 2;
  }
  // swizzled ds_read byte offsets within an 8KB slot
  int offA[8], offB[4];
#pragma unroll
  for (int m = 0; m < 8; ++m) {
    int rh = m * 16 + lrow;
    offA[m] = (rh * 4 + (lj ^ (rh & 3))) * 16;
  }
#pragma unroll
  for (int n = 0; n < 4; ++n) {
    int rh = (wn & 1) * 64 + n * 16 + lrow;
    offB[n] = (rh * 4 + (lj ^ (rh & 3))) * 16;
  }

  f32x4 acc[8][4];
#pragma unroll
  for (int m = 0; m < 8; ++m)
#pragma unroll
    for (int n = 0; n < 4; ++n) acc[m][n] = 0.f;

  const char* Ab = (const char*)A;
  const char* Bb = (const char*)B;
  auto STG = [&](int slot, int h, int ts) {
    const char* src = (h < 2 ? Ab : Bb) + e[h] + (uint32)ts * 64;
    gload_lds16(src, lds + slot * 8192 + tid * 16);
  };

  // prologue: steps 0 and 1 -> slots 0..7
#pragma unroll
  for (int g = 0; g < 8; ++g) STG(g, g & 3, g >> 2);

  int s0 = 0;   // slot of half 4t
  for (int t = 0; t < nt; ++t) {
    int aS = (s0 + wm) & 15;
    int bS = (s0 + 2 + (wn >> 1)) & 15;
    const char* aB = lds + aS * 8192;
    const char* bB = lds + bS * 8192;
    bf16x8 av[4], bv[4];

    // ---- phase 0: stage A halves of step t+2; compute m0-3 ----
    if (t < nt - 2) {
      STG((s0 + 8) & 15, 0, t + 2);
      STG((s0 + 9) & 15, 1, t + 2);
      wait_vmcnt<6>();
    } else if (t == nt - 2) {
      wait_vmcnt<4>();
    } else {
      wait_vmcnt<0>();
    }
    barrier_mem();
#pragma unroll
    for (int n = 0; n < 4; ++n) bv[n] = *(const bf16x8*)(bB + offB[n]);
#pragma unroll
    for (int i = 0; i < 4; ++i) av[i] = *(const bf16x8*)(aB + offA[i]);
    __builtin_amdgcn_s_setprio(1);
#pragma unroll
    for (int i = 0; i < 4; ++i)
#pragma unroll
      for (int n = 0; n < 4; ++n)
        acc[i][n] = __builtin_amdgcn_mfma_f32_16x16x32_bf16(av[i], bv[n], acc[i][n], 0, 0, 0);
    __builtin_amdgcn_s_setprio(0);

    // ---- phase 1: stage B halves of step t+2; compute m4-7 ----
    if (t < nt - 2) {
      STG((s0 + 10) & 15, 2, t + 2);
      STG((s0 + 11) & 15, 3, t + 2);
      wait_vmcnt<6>();
    } else if (t == nt - 2) {
      wait_vmcnt<4>();
    }
    barrier_mem();
#pragma unroll
    for (int i = 0; i < 4; ++i) av[i] = *(const bf16x8*)(aB + offA[4 + i]);
    __builtin_amdgcn_s_setprio(1);
#pragma unroll
    for (int i = 0; i < 4; ++i)
#pragma unroll
      for (int n = 0; n < 4; ++n)
        acc[4 + i][n] = __builtin_amdgcn_mfma_f32_16x16x32_bf16(av[i], bv[n], acc[4 + i][n], 0, 0, 0);
    __builtin_amdgcn_s_setprio(0);

    s0 = (s0 + 4) & 15;
  }

  // epilogue: C/D layout col=lane&15, row=(lane>>4)*4+j
#pragma unroll
  for (int n = 0; n < 4; ++n) {
    int col = bn0 + wn * 64 + n * 16 + lrow;
    if (col < N) {
      float bv2 = bias[col];
#pragma unroll
      for (int m = 0; m < 8; ++m) {
#pragma unroll
        for (int j = 0; j < 4; ++j) {
          int row = bm0 + wm * 128 + m * 16 + lj * 4 + j;
          float v = acc[m][n][j] + bv2;
          if (BF16OUT)
            ((unsigned short*)Cv)[(size_t)row * N + col] = f2bf(v);
          else
            ((float*)Cv)[(size_t)row * N + col] = v;
        }
      }
    }
  }
}

// stage-1 dual GEMM: grid 224 = 7(N) x 16(M) x 2(tensor), XCD-chunked (224%8==0)
__global__ __launch_bounds__(512, 2) void gemm_dual_256(
    const unsigned short* A0, const unsigned short* B0, const float* bias0, unsigned short* C0,
    const unsigned short* A1, const unsigned short* B1, const float* bias1, unsigned short* C1) {
  __shared__ char lds[131072];
  int wg = (blockIdx.x & 7) * 28 + (blockIdx.x >> 3);   // contiguous chunk per XCD
  int bz = wg >= 112;
  wg -= bz * 112;
  int by = wg / 7, bx = wg % 7;
  const unsigned short* A = bz ? A1 : A0;
  const unsigned short* B = bz ? B1 : B0;
  const float* bias = bz ? bias1 : bias0;
  unsigned short* C = bz ? C1 : C0;
  gemm256_core<true>(A, B, bias, C, lds, MM, D0D1, D0D1 / 32, by * 256, bx * 256);
}

// stage-3 GEMM: grid 192 = 12(N) x 16(M), XCD-chunked (192%8==0)
__global__ __launch_bounds__(512, 2) void gemm_out_256(
    const unsigned short* A, const unsigned short* B, const float* bias, float* C) {
  __shared__ char lds[131072];
  int wg = (blockIdx.x & 7) * 24 + (blockIdx.x >> 3);
  int by = wg / 12, bx = wg % 12;
  gemm256_core<false>(A, B, bias, C, lds, NOUT, MM, MM / 32, by * 256, bx * 256);
}

// ---------- stage 2: h in registers, async double-buffered weight staging ----------
__global__ __launch_bounds__(256, 2) void chunk_fuse2(
    const unsigned short* __restrict__ hb0, const unsigned short* __restrict__ hb1,
    const unsigned short* __restrict__ mWP, unsigned short* __restrict__ zb) {
  const int c = blockIdx.x, bt = blockIdx.y;
  __shared__ unsigned short wlds[2][WRANK];
  const int tid = threadIdx.x, wave = tid >> 6, lane = tid & 63;
  const int lrow = lane & 15, lj = lane >> 4;

  bf16x8 bzero;
  bzero = (__bf16)0.0f;

  bf16x8 a0[2][3], a1[2][3];
#pragma unroll
  for (int m = 0; m < 2; ++m)
#pragma unroll
    for (int kf = 0; kf < 3; ++kf) {
      int col = kf * 32 + lj * 8;
      bool valid = col < CSIZE;
      int row = bt * 128 + wave * 32 + m * 16 + lrow;
      size_t base = (size_t)row * MM + c * CSIZE + (valid ? col : 0);
      bf16x8 v0 = *(const bf16x8*)(hb0 + base);
      bf16x8 v1 = *(const bf16x8*)(hb1 + base);
      a0[m][kf] = valid ? v0 : bzero;
      a1[m][kf] = valid ? v1 : bzero;
    }

  const unsigned short* wsrc = mWP + (size_t)(c * RANK) * WRANK;
  auto STAGE = [&](int buf, int r) {
    const unsigned short* src = wsrc + (size_t)r * WRANK;
    char* dstb = (char*)&wlds[buf][0];
#pragma unroll
    for (int k = 0; k < 7; ++k) {
      int i = k * 256 + tid;
      if (i < WCH)
        gload_lds16(src + (size_t)i * 8, dstb + (k * 256 + wave * 64) * 16);
    }
  };

  f32x4 zacc[2][5];
#pragma unroll
  for (int m = 0; m < 2; ++m)
#pragma unroll
    for (int n = 0; n < 5; ++n) zacc[m][n] = 0.f;

  STAGE(0, 0);
  for (int r = 0; r < RANK; ++r) {
    int cur = r & 1;
    if (r < RANK - 1) {
      STAGE(cur ^ 1, r + 1);
      asm volatile("s_waitcnt vmcnt(7)" ::: "memory");
    } else {
      asm volatile("s_waitcnt vmcnt(0)" ::: "memory");
    }
    __builtin_amdgcn_s_barrier();

    float bs0[5], bs1[5];
#pragma unroll
    for (int n = 0; n < 5; ++n) {
      int s = n * 16 + lrow;
      bs0[n] = bf2f(wlds[cur][0 * WTEN + 80 * WST + s]);
      bs1[n] = bf2f(wlds[cur][1 * WTEN + 80 * WST + s]);
    }

#pragma unroll
    for (int m = 0; m < 2; ++m) {
      f32x4 y0[5], y1[5];
#pragma unroll
      for (int n = 0; n < 5; ++n) { y0[n] = 0.f; y1[n] = 0.f; }
#pragma unroll
      for (int kf = 0; kf < 3; ++kf) {
        int colb = kf * 32 + lj * 8;
        bool bvalid = colb < WST;
        int cb = bvalid ? colb : 0;
#pragma unroll
        for (int n = 0; n < 5; ++n) {
          int tt = n * 16 + lrow;
          bf16x8 b0 = *(const bf16x8*)&wlds[cur][0 * WTEN + tt * WST + cb];
          bf16x8 b1 = *(const bf16x8*)&wlds[cur][1 * WTEN + tt * WST + cb];
          if (!bvalid) { b0 = bzero; b1 = bzero; }
          y0[n] = __builtin_amdgcn_mfma_f32_16x16x32_bf16(a0[m][kf], b0, y0[n], 0, 0, 0);
          y1[n] = __builtin_amdgcn_mfma_f32_16x16x32_bf16(a1[m][kf], b1, y1[n], 0, 0, 0);
        }
      }
#pragma unroll
      for (int n = 0; n < 5; ++n)
#pragma unroll
        for (int j = 0; j < 4; ++j)
          zacc[m][n][j] += (y0[n][j] + bs0[n]) * (y1[n][j] + bs1[n]);
    }
    __builtin_amdgcn_s_barrier();
  }

#pragma unroll
  for (int m = 0; m < 2; ++m) {
    float g[5][4];
    float ssj[4] = {0.f, 0.f, 0.f, 0.f};
#pragma unroll
    for (int n = 0; n < 5; ++n)
#pragma unroll
      for (int j = 0; j < 4; ++j) {
        float v = zacc[m][n][j];
        float a = sqrtf(fabsf(v));
        float gv = v < 0.f ? -a : a;
        g[n][j] = gv;
        ssj[j] += gv * gv;
      }
#pragma unroll
    for (int j = 0; j < 4; ++j) {
      float s = ssj[j];
      s += __shfl_xor(s, 1);
      s += __shfl_xor(s, 2);
      s += __shfl_xor(s, 4);
      s += __shfl_xor(s, 8);
      float nrm = sqrtf(s);
      nrm = nrm > 1e-12f ? nrm : 1e-12f;
      ssj[j] = 1.f / nrm;
    }
#pragma unroll
    for (int n = 0; n < 5; ++n) {
      int scol = n * 16 + lrow;
#pragma unroll
      for (int j = 0; j < 4; ++j) {
        int row = bt * 128 + wave * 32 + m * 16 + lj * 4 + j;
        zb[(size_t)row * MM + c * CSIZE + scol] = f2bf(g[n][j] * ssj[j]);
      }
    }
  }
}

// ---------- workspace layout (bytes) ----------
#define OFF_XB0   ((size_t)0)
#define OFF_XB1   (OFF_XB0 + (size_t)BATCH * D0D1 * 2)
#define OFF_WB0   (OFF_XB1 + (size_t)BATCH * D0D1 * 2)
#define OFF_WB1   (OFF_WB0 + (size_t)MM * D0D1 * 2)
#define OFF_WOUTB (OFF_WB1 + (size_t)MM * D0D1 * 2)
#define OFF_HB0   (OFF_WOUTB + (size_t)NOUT * MM * 2)
#define OFF_HB1   (OFF_HB0 + (size_t)BATCH * MM * 2)
#define OFF_ZB    (OFF_HB1 + (size_t)BATCH * MM * 2)
#define WS_NEED   (OFF_ZB + (size_t)BATCH * MM * 2)
#define OFF_MWP   OFF_XB0   // mWP aliases xb0, packed after gemm_dual consumed it

extern "C" void kernel_launch(void* const* d_in, const int* in_sizes, int n_in,
                              void* d_out, int out_size, void* d_ws, size_t ws_size,
                              hipStream_t stream) {
  const float* x0   = (const float*)d_in[0];
  const float* x1   = (const float*)d_in[1];
  const float* W0   = (const float*)d_in[2];
  const float* b0   = (const float*)d_in[3];
  const float* W1   = (const float*)d_in[4];
  const float* b1   = (const float*)d_in[5];
  const float* mW0  = (const float*)d_in[6];
  const float* mb0  = (const float*)d_in[7];
  const float* mW1  = (const float*)d_in[8];
  const float* mb1  = (const float*)d_in[9];
  const float* Wout = (const float*)d_in[10];
  const float* bout = (const float*)d_in[11];

  if (ws_size < WS_NEED) return;

  char* ws = (char*)d_ws;
  unsigned short* xb0   = (unsigned short*)(ws + OFF_XB0);
  unsigned short* xb1   = (unsigned short*)(ws + OFF_XB1);
  unsigned short* Wb0   = (unsigned short*)(ws + OFF_WB0);
  unsigned short* Wb1   = (unsigned short*)(ws + OFF_WB1);
  unsigned short* Woutb = (unsigned short*)(ws + OFF_WOUTB);
  unsigned short* hb0   = (unsigned short*)(ws + OFF_HB0);
  unsigned short* hb1   = (unsigned short*)(ws + OFF_HB1);
  unsigned short* zb    = (unsigned short*)(ws + OFF_ZB);
  unsigned short* mWP   = (unsigned short*)(ws + OFF_MWP);

  auto cast = [&](const float* s, unsigned short* d, int n) {
    int blocks = (n / 8 + 255) / 256;
    hipLaunchKernelGGL(cast_bf16_k, dim3(blocks), dim3(256), 0, stream, s, d, n);
  };
  cast(x0, xb0, BATCH * D0D1);
  cast(x1, xb1, BATCH * D0D1);
  cast(W0, Wb0, MM * D0D1);
  cast(W1, Wb1, MM * D0D1);
  cast(Wout, Woutb, NOUT * MM);

  // stage 1: h0,h1 = x@W^T + b  -> bf16 [4096][1600]
  hipLaunchKernelGGL(gemm_dual_256, dim3(224), dim3(512), 0, stream,
                     xb0, Wb0, b0, hb0, xb1, Wb1, b1, hb1);

  // pack mW+mb (into xb0's space, now free)
  hipLaunchKernelGGL(cast_mwp_k, dim3((WCH + 255) / 256, RANK, NCHUNKS), dim3(256), 0, stream,
                     mW0, mb0, mW1, mb1, mWP);

  // stage 2: chunk MM + bilinear + signed sqrt + L2 norm -> zb bf16
  hipLaunchKernelGGL(chunk_fuse2, dim3(NCHUNKS, BATCH / 128), dim3(256), 0, stream,
                     hb0, hb1, mWP, zb);

  // stage 3: out = zn@Wout^T + bout -> f32 [4096][3000]
  hipLaunchKernelGGL(gemm_out_256, dim3(192), dim3(512), 0, stream,
                     zb, Woutb, bout, (float*)d_out);
}

// Round 6
// 224.888 us; speedup vs baseline: 1.4948x; 1.0111x over previous
//
#include <hip/hip_runtime.h>

typedef unsigned int uint32;
typedef __bf16 bf16x8 __attribute__((ext_vector_type(8)));
typedef float f32x4 __attribute__((ext_vector_type(4)));

typedef __attribute__((address_space(1))) unsigned int as1_uint;
typedef __attribute__((address_space(3))) unsigned int as3_uint;

// ---------- constants ----------
#define BATCH 4096
#define D0D1 2048
#define MM 1600
#define NCHUNKS 20
#define RANK 15
#define CSIZE 80
#define TDIM 1200   // SIZE*RANK
#define NOUT 3000

// packed weight layout for stage 2 (unchanged)
#define WST 88
#define WTROWS 81
#define WTEN (WTROWS * WST)
#define WRANK (2 * WTEN)
#define WCH (WRANK * 2 / 16)

__device__ __forceinline__ unsigned short f2bf(float f) {
  unsigned int u = __builtin_bit_cast(unsigned int, f);
  u = (u + 0x7fffu + ((u >> 16) & 1u)) >> 16;
  return (unsigned short)u;
}
__device__ __forceinline__ float bf2f(unsigned short u) {
  return __builtin_bit_cast(float, (uint32)u << 16);
}

__device__ __forceinline__ void gload_lds16(const void* g, void* lds) {
  __builtin_amdgcn_global_load_lds((as1_uint*)g, (as3_uint*)lds, 16, 0, 0);
}

template <int N>
__device__ __forceinline__ void wait_vmcnt() {
  asm volatile("s_waitcnt vmcnt(%0)" :: "n"(N) : "memory");
}
__device__ __forceinline__ void barrier_mem() {
  asm volatile("s_barrier" ::: "memory");
}

// ---------- cast f32 -> bf16, 8 elems/thread ----------
__global__ __launch_bounds__(256) void cast_bf16_k(const float* __restrict__ src,
                                                   unsigned short* __restrict__ dst, int n) {
  int i = (blockIdx.x * 256 + threadIdx.x) * 8;
  if (i >= n) return;
  float4 v0 = *(const float4*)(src + i);
  float4 v1 = *(const float4*)(src + i + 4);
  uint4 o;
  o.x = (uint32)f2bf(v0.x) | ((uint32)f2bf(v0.y) << 16);
  o.y = (uint32)f2bf(v0.z) | ((uint32)f2bf(v0.w) << 16);
  o.z = (uint32)f2bf(v1.x) | ((uint32)f2bf(v1.y) << 16);
  o.w = (uint32)f2bf(v1.z) | ((uint32)f2bf(v1.w) << 16);
  *(uint4*)(dst + i) = o;
}

// ---------- pack mW + mb into padded conflict-free layout (unchanged) ----------
__global__ __launch_bounds__(256) void cast_mwp_k(
    const float* __restrict__ mW0, const float* __restrict__ mb0,
    const float* __restrict__ mW1, const float* __restrict__ mb1,
    unsigned short* __restrict__ mWP) {
  const int c = blockIdx.z, r = blockIdx.y;
  int i = blockIdx.x * 256 + threadIdx.x;
  if (i >= WCH) return;
  int e = i * 8;
  int tensor = e / WTEN;
  int rem = e - tensor * WTEN;
  int row = rem / WST;
  int col0 = rem - row * WST;

  float v[8];
  if (col0 >= CSIZE) {
#pragma unroll
    for (int k = 0; k < 8; ++k) v[k] = 0.f;
  } else if (row < CSIZE) {
    const float* src = (tensor ? mW1 : mW0) +
                       ((size_t)c * TDIM + (size_t)r * CSIZE + row) * CSIZE + col0;
#pragma unroll
    for (int k = 0; k < 8; ++k) v[k] = src[k];
  } else {
    const float* src = (tensor ? mb1 : mb0) + (size_t)c * TDIM + (size_t)r * CSIZE + col0;
#pragma unroll
    for (int k = 0; k < 8; ++k) v[k] = src[k];
  }
  uint4 o;
  o.x = (uint32)f2bf(v[0]) | ((uint32)f2bf(v[1]) << 16);
  o.y = (uint32)f2bf(v[2]) | ((uint32)f2bf(v[3]) << 16);
  o.z = (uint32)f2bf(v[4]) | ((uint32)f2bf(v[5]) << 16);
  o.w = (uint32)f2bf(v[6]) | ((uint32)f2bf(v[7]) << 16);
  *(uint4*)(mWP + ((size_t)(c * RANK + r)) * WRANK + e) = o;
}

// ---------- NT GEMM core v4.1: 256x256 tile, BK=32, phase-pipelined 16-slot ring ----------
// 8 waves (2M x 4N), wave owns 128x64 C. Half-tile = 128 rows x 32 K bf16 = 8KB;
// step t occupies slots (4t..4t+3)&15: {A rows0-127, A rows128-255, B0-127, B128-255}.
// Granule swizzle kgsw = kg ^ ((row>>1)&3)  [round-3 MEASURED 0-conflict formula;
// round 5's (row&3) variant re-introduced 4-way conflicts = 5.5M counter].
// Bank-start = 16*(row&1) + 4*kgsw -> 8 distinct quads, 2 lanes each (free).
// Staging pre-permutes the GLOBAL source per lane (LDS dst linear, rule 21);
// ds_read applies the same XOR.
// Schedule per step: 2 phases of {stage 2 halves of step t+2; vmcnt(6); s_barrier;
// ds_read; setprio(1); 16 MFMA; setprio(0)}. vmcnt drains only in the tail.
template <bool BF16OUT>
__device__ __forceinline__ void gemm256_core(const unsigned short* __restrict__ A,
                                             const unsigned short* __restrict__ B,
                                             const float* __restrict__ bias,
                                             void* __restrict__ Cv,
                                             char* lds, int N, int K, int nt,
                                             int bm0, int bn0) {
  const int tid = threadIdx.x;
  const int wave = tid >> 6, lane = tid & 63;
  const int wm = wave >> 2, wn = wave & 3;
  const int lrow = lane & 15, lj = lane >> 4;

  // staging source byte offset per half-tile (1 granule = 16B per thread per half)
  uint32 e[4];
#pragma unroll
  for (int h = 0; h < 4; ++h) {
    int r = tid >> 2;                       // row 0..127 within half
    int kg = (tid & 3) ^ ((r >> 1) & 3);    // inverse swizzle on the source side
    int row = (h < 2) ? (bm0 + h * 128 + r) : (bn0 + (h - 2) * 128 + r);
    if (h >= 2 && row > N - 1) row = N - 1; // clamp keeps ragged-N loads in-bounds
    e[h] = (uint32)(row * K + kg * 8) * 2;
  }
  // swizzled ds_read byte offsets within an 8KB slot
  int offA[8], offB[4];
#pragma unroll
  for (int m = 0; m < 8; ++m) {
    int rh = m * 16 + lrow;
    offA[m] = (rh * 4 + (lj ^ ((rh >> 1) & 3))) * 16;
  }
#pragma unroll
  for (int n = 0; n < 4; ++n) {
    int rh = (wn & 1) * 64 + n * 16 + lrow;
    offB[n] = (rh * 4 + (lj ^ ((rh >> 1) & 3))) * 16;
  }

  f32x4 acc[8][4];
#pragma unroll
  for (int m = 0; m < 8; ++m)
#pragma unroll
    for (int n = 0; n < 4; ++n) acc[m][n] = 0.f;

  const char* Ab = (const char*)A;
  const char* Bb = (const char*)B;
  auto STG = [&](int slot, int h, int ts) {
    const char* src = (h < 2 ? Ab : Bb) + e[h] + (uint32)ts * 64;
    gload_lds16(src, lds + slot * 8192 + tid * 16);
  };

  // prologue: steps 0 and 1 -> slots 0..7
#pragma unroll
  for (int g = 0; g < 8; ++g) STG(g, g & 3, g >> 2);

  int s0 = 0;   // slot of half 4t
  for (int t = 0; t < nt; ++t) {
    int aS = (s0 + wm) & 15;
    int bS = (s0 + 2 + (wn >> 1)) & 15;
    const char* aB = lds + aS * 8192;
    const char* bB = lds + bS * 8192;
    bf16x8 av[4], bv[4];

    // ---- phase 0: stage A halves of step t+2; compute m0-3 ----
    if (t < nt - 2) {
      STG((s0 + 8) & 15, 0, t + 2);
      STG((s0 + 9) & 15, 1, t + 2);
      wait_vmcnt<6>();
    } else if (t == nt - 2) {
      wait_vmcnt<4>();
    } else {
      wait_vmcnt<0>();
    }
    barrier_mem();
#pragma unroll
    for (int n = 0; n < 4; ++n) bv[n] = *(const bf16x8*)(bB + offB[n]);
#pragma unroll
    for (int i = 0; i < 4; ++i) av[i] = *(const bf16x8*)(aB + offA[i]);
    __builtin_amdgcn_s_setprio(1);
#pragma unroll
    for (int i = 0; i < 4; ++i)
#pragma unroll
      for (int n = 0; n < 4; ++n)
        acc[i][n] = __builtin_amdgcn_mfma_f32_16x16x32_bf16(av[i], bv[n], acc[i][n], 0, 0, 0);
    __builtin_amdgcn_s_setprio(0);

    // ---- phase 1: stage B halves of step t+2; compute m4-7 ----
    if (t < nt - 2) {
      STG((s0 + 10) & 15, 2, t + 2);
      STG((s0 + 11) & 15, 3, t + 2);
      wait_vmcnt<6>();
    } else if (t == nt - 2) {
      wait_vmcnt<4>();
    }
    barrier_mem();
#pragma unroll
    for (int i = 0; i < 4; ++i) av[i] = *(const bf16x8*)(aB + offA[4 + i]);
    __builtin_amdgcn_s_setprio(1);
#pragma unroll
    for (int i = 0; i < 4; ++i)
#pragma unroll
      for (int n = 0; n < 4; ++n)
        acc[4 + i][n] = __builtin_amdgcn_mfma_f32_16x16x32_bf16(av[i], bv[n], acc[4 + i][n], 0, 0, 0);
    __builtin_amdgcn_s_setprio(0);

    s0 = (s0 + 4) & 15;
  }

  // epilogue: C/D layout col=lane&15, row=(lane>>4)*4+j
#pragma unroll
  for (int n = 0; n < 4; ++n) {
    int col = bn0 + wn * 64 + n * 16 + lrow;
    if (col < N) {
      float bv2 = bias[col];
#pragma unroll
      for (int m = 0; m < 8; ++m) {
#pragma unroll
        for (int j = 0; j < 4; ++j) {
          int row = bm0 + wm * 128 + m * 16 + lj * 4 + j;
          float v = acc[m][n][j] + bv2;
          if (BF16OUT)
            ((unsigned short*)Cv)[(size_t)row * N + col] = f2bf(v);
          else
            ((float*)Cv)[(size_t)row * N + col] = v;
        }
      }
    }
  }
}

// stage-1 dual GEMM: grid 224 = 7(N) x 16(M) x 2(tensor), XCD-chunked (224%8==0)
__global__ __launch_bounds__(512, 2) void gemm_dual_256(
    const unsigned short* A0, const unsigned short* B0, const float* bias0, unsigned short* C0,
    const unsigned short* A1, const unsigned short* B1, const float* bias1, unsigned short* C1) {
  __shared__ char lds[131072];
  int wg = (blockIdx.x & 7) * 28 + (blockIdx.x >> 3);   // contiguous chunk per XCD
  int bz = wg >= 112;
  wg -= bz * 112;
  int by = wg / 7, bx = wg % 7;
  const unsigned short* A = bz ? A1 : A0;
  const unsigned short* B = bz ? B1 : B0;
  const float* bias = bz ? bias1 : bias0;
  unsigned short* C = bz ? C1 : C0;
  gemm256_core<true>(A, B, bias, C, lds, MM, D0D1, D0D1 / 32, by * 256, bx * 256);
}

// stage-3 GEMM: grid 192 = 12(N) x 16(M), XCD-chunked (192%8==0)
__global__ __launch_bounds__(512, 2) void gemm_out_256(
    const unsigned short* A, const unsigned short* B, const float* bias, float* C) {
  __shared__ char lds[131072];
  int wg = (blockIdx.x & 7) * 24 + (blockIdx.x >> 3);
  int by = wg / 12, bx = wg % 12;
  gemm256_core<false>(A, B, bias, C, lds, NOUT, MM, MM / 32, by * 256, bx * 256);
}

// ---------- stage 2: h in registers, async double-buffered weight staging ----------
__global__ __launch_bounds__(256, 2) void chunk_fuse2(
    const unsigned short* __restrict__ hb0, const unsigned short* __restrict__ hb1,
    const unsigned short* __restrict__ mWP, unsigned short* __restrict__ zb) {
  const int c = blockIdx.x, bt = blockIdx.y;
  __shared__ unsigned short wlds[2][WRANK];
  const int tid = threadIdx.x, wave = tid >> 6, lane = tid & 63;
  const int lrow = lane & 15, lj = lane >> 4;

  bf16x8 bzero;
  bzero = (__bf16)0.0f;

  bf16x8 a0[2][3], a1[2][3];
#pragma unroll
  for (int m = 0; m < 2; ++m)
#pragma unroll
    for (int kf = 0; kf < 3; ++kf) {
      int col = kf * 32 + lj * 8;
      bool valid = col < CSIZE;
      int row = bt * 128 + wave * 32 + m * 16 + lrow;
      size_t base = (size_t)row * MM + c * CSIZE + (valid ? col : 0);
      bf16x8 v0 = *(const bf16x8*)(hb0 + base);
      bf16x8 v1 = *(const bf16x8*)(hb1 + base);
      a0[m][kf] = valid ? v0 : bzero;
      a1[m][kf] = valid ? v1 : bzero;
    }

  const unsigned short* wsrc = mWP + (size_t)(c * RANK) * WRANK;
  auto STAGE = [&](int buf, int r) {
    const unsigned short* src = wsrc + (size_t)r * WRANK;
    char* dstb = (char*)&wlds[buf][0];
#pragma unroll
    for (int k = 0; k < 7; ++k) {
      int i = k * 256 + tid;
      if (i < WCH)
        gload_lds16(src + (size_t)i * 8, dstb + (k * 256 + wave * 64) * 16);
    }
  };

  f32x4 zacc[2][5];
#pragma unroll
  for (int m = 0; m < 2; ++m)
#pragma unroll
    for (int n = 0; n < 5; ++n) zacc[m][n] = 0.f;

  STAGE(0, 0);
  for (int r = 0; r < RANK; ++r) {
    int cur = r & 1;
    if (r < RANK - 1) {
      STAGE(cur ^ 1, r + 1);
      asm volatile("s_waitcnt vmcnt(7)" ::: "memory");
    } else {
      asm volatile("s_waitcnt vmcnt(0)" ::: "memory");
    }
    __builtin_amdgcn_s_barrier();

    float bs0[5], bs1[5];
#pragma unroll
    for (int n = 0; n < 5; ++n) {
      int s = n * 16 + lrow;
      bs0[n] = bf2f(wlds[cur][0 * WTEN + 80 * WST + s]);
      bs1[n] = bf2f(wlds[cur][1 * WTEN + 80 * WST + s]);
    }

#pragma unroll
    for (int m = 0; m < 2; ++m) {
      f32x4 y0[5], y1[5];
#pragma unroll
      for (int n = 0; n < 5; ++n) { y0[n] = 0.f; y1[n] = 0.f; }
#pragma unroll
      for (int kf = 0; kf < 3; ++kf) {
        int colb = kf * 32 + lj * 8;
        bool bvalid = colb < WST;
        int cb = bvalid ? colb : 0;
#pragma unroll
        for (int n = 0; n < 5; ++n) {
          int tt = n * 16 + lrow;
          bf16x8 b0 = *(const bf16x8*)&wlds[cur][0 * WTEN + tt * WST + cb];
          bf16x8 b1 = *(const bf16x8*)&wlds[cur][1 * WTEN + tt * WST + cb];
          if (!bvalid) { b0 = bzero; b1 = bzero; }
          y0[n] = __builtin_amdgcn_mfma_f32_16x16x32_bf16(a0[m][kf], b0, y0[n], 0, 0, 0);
          y1[n] = __builtin_amdgcn_mfma_f32_16x16x32_bf16(a1[m][kf], b1, y1[n], 0, 0, 0);
        }
      }
#pragma unroll
      for (int n = 0; n < 5; ++n)
#pragma unroll
        for (int j = 0; j < 4; ++j)
          zacc[m][n][j] += (y0[n][j] + bs0[n]) * (y1[n][j] + bs1[n]);
    }
    __builtin_amdgcn_s_barrier();
  }

#pragma unroll
  for (int m = 0; m < 2; ++m) {
    float g[5][4];
    float ssj[4] = {0.f, 0.f, 0.f, 0.f};
#pragma unroll
    for (int n = 0; n < 5; ++n)
#pragma unroll
      for (int j = 0; j < 4; ++j) {
        float v = zacc[m][n][j];
        float a = sqrtf(fabsf(v));
        float gv = v < 0.f ? -a : a;
        g[n][j] = gv;
        ssj[j] += gv * gv;
      }
#pragma unroll
    for (int j = 0; j < 4; ++j) {
      float s = ssj[j];
      s += __shfl_xor(s, 1);
      s += __shfl_xor(s, 2);
      s += __shfl_xor(s, 4);
      s += __shfl_xor(s, 8);
      float nrm = sqrtf(s);
      nrm = nrm > 1e-12f ? nrm : 1e-12f;
      ssj[j] = 1.f / nrm;
    }
#pragma unroll
    for (int n = 0; n < 5; ++n) {
      int scol = n * 16 + lrow;
#pragma unroll
      for (int j = 0; j < 4; ++j) {
        int row = bt * 128 + wave * 32 + m * 16 + lj * 4 + j;
        zb[(size_t)row * MM + c * CSIZE + scol] = f2bf(g[n][j] * ssj[j]);
      }
    }
  }
}

// ---------- workspace layout (bytes) ----------
#define OFF_XB0   ((size_t)0)
#define OFF_XB1   (OFF_XB0 + (size_t)BATCH * D0D1 * 2)
#define OFF_WB0   (OFF_XB1 + (size_t)BATCH * D0D1 * 2)
#define OFF_WB1   (OFF_WB0 + (size_t)MM * D0D1 * 2)
#define OFF_WOUTB (OFF_WB1 + (size_t)MM * D0D1 * 2)
#define OFF_HB0   (OFF_WOUTB + (size_t)NOUT * MM * 2)
#define OFF_HB1   (OFF_HB0 + (size_t)BATCH * MM * 2)
#define OFF_ZB    (OFF_HB1 + (size_t)BATCH * MM * 2)
#define WS_NEED   (OFF_ZB + (size_t)BATCH * MM * 2)
#define OFF_MWP   OFF_XB0   // mWP aliases xb0, packed after gemm_dual consumed it

extern "C" void kernel_launch(void* const* d_in, const int* in_sizes, int n_in,
                              void* d_out, int out_size, void* d_ws, size_t ws_size,
                              hipStream_t stream) {
  const float* x0   = (const float*)d_in[0];
  const float* x1   = (const float*)d_in[1];
  const float* W0   = (const float*)d_in[2];
  const float* b0   = (const float*)d_in[3];
  const float* W1   = (const float*)d_in[4];
  const float* b1   = (const float*)d_in[5];
  const float* mW0  = (const float*)d_in[6];
  const float* mb0  = (const float*)d_in[7];
  const float* mW1  = (const float*)d_in[8];
  const float* mb1  = (const float*)d_in[9];
  const float* Wout = (const float*)d_in[10];
  const float* bout = (const float*)d_in[11];

  if (ws_size < WS_NEED) return;

  char* ws = (char*)d_ws;
  unsigned short* xb0   = (unsigned short*)(ws + OFF_XB0);
  unsigned short* xb1   = (unsigned short*)(ws + OFF_XB1);
  unsigned short* Wb0   = (unsigned short*)(ws + OFF_WB0);
  unsigned short* Wb1   = (unsigned short*)(ws + OFF_WB1);
  unsigned short* Woutb = (unsigned short*)(ws + OFF_WOUTB);
  unsigned short* hb0   = (unsigned short*)(ws + OFF_HB0);
  unsigned short* hb1   = (unsigned short*)(ws + OFF_HB1);
  unsigned short* zb    = (unsigned short*)(ws + OFF_ZB);
  unsigned short* mWP   = (unsigned short*)(ws + OFF_MWP);

  auto cast = [&](const float* s, unsigned short* d, int n) {
    int blocks = (n / 8 + 255) / 256;
    hipLaunchKernelGGL(cast_bf16_k, dim3(blocks), dim3(256), 0, stream, s, d, n);
  };
  cast(x0, xb0, BATCH * D0D1);
  cast(x1, xb1, BATCH * D0D1);
  cast(W0, Wb0, MM * D0D1);
  cast(W1, Wb1, MM * D0D1);
  cast(Wout, Woutb, NOUT * MM);

  // stage 1: h0,h1 = x@W^T + b  -> bf16 [4096][1600]
  hipLaunchKernelGGL(gemm_dual_256, dim3(224), dim3(512), 0, stream,
                     xb0, Wb0, b0, hb0, xb1, Wb1, b1, hb1);

  // pack mW+mb (into xb0's space, now free)
  hipLaunchKernelGGL(cast_mwp_k, dim3((WCH + 255) / 256, RANK, NCHUNKS), dim3(256), 0, stream,
                     mW0, mb0, mW1, mb1, mWP);

  // stage 2: chunk MM + bilinear + signed sqrt + L2 norm -> zb bf16
  hipLaunchKernelGGL(chunk_fuse2, dim3(NCHUNKS, BATCH / 128), dim3(256), 0, stream,
                     hb0, hb1, mWP, zb);

  // stage 3: out = zn@Wout^T + bout -> f32 [4096][3000]
  hipLaunchKernelGGL(gemm_out_256, dim3(192), dim3(512), 0, stream,
                     zb, Woutb, bout, (float*)d_out);
}

// Round 7
// 224.570 us; speedup vs baseline: 1.4969x; 1.0014x over previous
//
#include <hip/hip_runtime.h>

typedef unsigned int uint32;
typedef __bf16 bf16x8 __attribute__((ext_vector_type(8)));
typedef float f32x4 __attribute__((ext_vector_type(4)));

typedef __attribute__((address_space(1))) unsigned int as1_uint;
typedef __attribute__((address_space(3))) unsigned int as3_uint;

// ---------- constants ----------
#define BATCH 4096
#define D0D1 2048
#define MM 1600
#define NCHUNKS 20
#define RANK 15
#define CSIZE 80
#define TDIM 1200   // SIZE*RANK
#define NOUT 3000

// packed weight layout for stage 2 (unchanged)
#define WST 88
#define WTROWS 81
#define WTEN (WTROWS * WST)
#define WRANK (2 * WTEN)
#define WCH (WRANK * 2 / 16)

__device__ __forceinline__ unsigned short f2bf(float f) {
  unsigned int u = __builtin_bit_cast(unsigned int, f);
  u = (u + 0x7fffu + ((u >> 16) & 1u)) >> 16;
  return (unsigned short)u;
}
__device__ __forceinline__ float bf2f(unsigned short u) {
  return __builtin_bit_cast(float, (uint32)u << 16);
}

__device__ __forceinline__ void gload_lds16(const void* g, void* lds) {
  __builtin_amdgcn_global_load_lds((as1_uint*)g, (as3_uint*)lds, 16, 0, 0);
}

template <int N>
__device__ __forceinline__ void wait_vmcnt() {
  asm volatile("s_waitcnt vmcnt(%0)" :: "n"(N) : "memory");
}
__device__ __forceinline__ void barrier_mem() {
  asm volatile("s_barrier" ::: "memory");
}

// ---------- cast f32 -> bf16, 8 elems/thread ----------
__global__ __launch_bounds__(256) void cast_bf16_k(const float* __restrict__ src,
                                                   unsigned short* __restrict__ dst, int n) {
  int i = (blockIdx.x * 256 + threadIdx.x) * 8;
  if (i >= n) return;
  float4 v0 = *(const float4*)(src + i);
  float4 v1 = *(const float4*)(src + i + 4);
  uint4 o;
  o.x = (uint32)f2bf(v0.x) | ((uint32)f2bf(v0.y) << 16);
  o.y = (uint32)f2bf(v0.z) | ((uint32)f2bf(v0.w) << 16);
  o.z = (uint32)f2bf(v1.x) | ((uint32)f2bf(v1.y) << 16);
  o.w = (uint32)f2bf(v1.z) | ((uint32)f2bf(v1.w) << 16);
  *(uint4*)(dst + i) = o;
}

// ---------- pack mW + mb into padded conflict-free layout (unchanged) ----------
__global__ __launch_bounds__(256) void cast_mwp_k(
    const float* __restrict__ mW0, const float* __restrict__ mb0,
    const float* __restrict__ mW1, const float* __restrict__ mb1,
    unsigned short* __restrict__ mWP) {
  const int c = blockIdx.z, r = blockIdx.y;
  int i = blockIdx.x * 256 + threadIdx.x;
  if (i >= WCH) return;
  int e = i * 8;
  int tensor = e / WTEN;
  int rem = e - tensor * WTEN;
  int row = rem / WST;
  int col0 = rem - row * WST;

  float v[8];
  if (col0 >= CSIZE) {
#pragma unroll
    for (int k = 0; k < 8; ++k) v[k] = 0.f;
  } else if (row < CSIZE) {
    const float* src = (tensor ? mW1 : mW0) +
                       ((size_t)c * TDIM + (size_t)r * CSIZE + row) * CSIZE + col0;
#pragma unroll
    for (int k = 0; k < 8; ++k) v[k] = src[k];
  } else {
    const float* src = (tensor ? mb1 : mb0) + (size_t)c * TDIM + (size_t)r * CSIZE + col0;
#pragma unroll
    for (int k = 0; k < 8; ++k) v[k] = src[k];
  }
  uint4 o;
  o.x = (uint32)f2bf(v[0]) | ((uint32)f2bf(v[1]) << 16);
  o.y = (uint32)f2bf(v[2]) | ((uint32)f2bf(v[3]) << 16);
  o.z = (uint32)f2bf(v[4]) | ((uint32)f2bf(v[5]) << 16);
  o.w = (uint32)f2bf(v[6]) | ((uint32)f2bf(v[7]) << 16);
  *(uint4*)(mWP + ((size_t)(c * RANK + r)) * WRANK + e) = o;
}

// ---------- NT GEMM core v5: 256x256, BK=32, 16-slot ring, m201-style phases ----------
// 8 waves (2M x 4N), wave owns 128x64 C. Half-tile slot = 128 rows x 32 K = 8KB.
// Granule swizzle kgsw = kg ^ ((row>>1)&3) [measured 0-conflict, rounds 3/6].
// m201-ported schedule: ds_reads + STG issued BEFORE the opening barrier (latency
// hides under barrier wait + other waves' MFMA); MFMA cluster sandwiched by two
// barriers; ONE counted vmcnt(8) per step (phase 1) guaranteeing step t+1 landed;
// prefetch depth 3 steps (12 of 16 slots in flight); tail drains 8->4->0.
// Race invariants: (a) per-wave vmcnt(8) precedes the ph1 opening barrier, so after
// that barrier ALL waves' contributions to step t+1 are in LDS -> ph0 reads safe;
// (b) STG of step t+3 (slots of t-1) is issued after t-1 ph1's closing barrier,
// and t-1's last reads completed before its MFMA (lgkm) which precedes that
// barrier; (c) sched_barrier(0) pins MFMA+lgkm inside the barrier pair.
template <bool BF16OUT>
__device__ __forceinline__ void gemm256_core(const unsigned short* __restrict__ A,
                                             const unsigned short* __restrict__ B,
                                             const float* __restrict__ bias,
                                             void* __restrict__ Cv,
                                             char* lds, int N, int K, int nt,
                                             int bm0, int bn0) {
  const int tid = threadIdx.x;
  const int wave = tid >> 6, lane = tid & 63;
  const int wm = wave >> 2, wn = wave & 3;
  const int lrow = lane & 15, lj = lane >> 4;

  // staging source byte offset per half-tile (1 granule = 16B per thread per half)
  uint32 e[4];
#pragma unroll
  for (int h = 0; h < 4; ++h) {
    int r = tid >> 2;                       // row 0..127 within half
    int kg = (tid & 3) ^ ((r >> 1) & 3);    // inverse swizzle on the source side
    int row = (h < 2) ? (bm0 + h * 128 + r) : (bn0 + (h - 2) * 128 + r);
    if (h >= 2 && row > N - 1) row = N - 1; // clamp keeps ragged-N loads in-bounds
    e[h] = (uint32)(row * K + kg * 8) * 2;
  }
  // swizzled ds_read byte offsets within an 8KB slot
  int offA[8], offB[4];
#pragma unroll
  for (int m = 0; m < 8; ++m) {
    int rh = m * 16 + lrow;
    offA[m] = (rh * 4 + (lj ^ ((rh >> 1) & 3))) * 16;
  }
#pragma unroll
  for (int n = 0; n < 4; ++n) {
    int rh = (wn & 1) * 64 + n * 16 + lrow;
    offB[n] = (rh * 4 + (lj ^ ((rh >> 1) & 3))) * 16;
  }

  f32x4 acc[8][4];
#pragma unroll
  for (int m = 0; m < 8; ++m)
#pragma unroll
    for (int n = 0; n < 4; ++n) acc[m][n] = 0.f;

  const char* Ab = (const char*)A;
  const char* Bb = (const char*)B;
  auto STG = [&](int slot, int h, int ts) {
    const char* src = (h < 2 ? Ab : Bb) + e[h] + (uint32)ts * 64;
    gload_lds16(src, lds + slot * 8192 + tid * 16);
  };

  // prologue: steps 0..2 -> slots 0..11
#pragma unroll
  for (int g = 0; g < 12; ++g) STG(g, g & 3, g >> 2);
  wait_vmcnt<8>();    // step 0 fully landed (steps 1,2 = 8 loads still in flight)
  barrier_mem();

  int s0 = 0;   // slot of half 4t
  for (int t = 0; t < nt; ++t) {
    const char* aB = lds + ((s0 + wm) & 15) * 8192;
    const char* bB = lds + ((s0 + 2 + (wn >> 1)) & 15) * 8192;
    bf16x8 av[4], bv[4], aw[4];

    // ---- phase 0: read frags early, issue A-halves of t+3, barrier, MFMA m0-3 ----
#pragma unroll
    for (int n = 0; n < 4; ++n) bv[n] = *(const bf16x8*)(bB + offB[n]);
#pragma unroll
    for (int i = 0; i < 4; ++i) av[i] = *(const bf16x8*)(aB + offA[i]);
    if (t < nt - 3) {
      STG((s0 + 12) & 15, 0, t + 3);
      STG((s0 + 13) & 15, 1, t + 3);
    }
    barrier_mem();
    __builtin_amdgcn_s_setprio(1);
#pragma unroll
    for (int i = 0; i < 4; ++i)
#pragma unroll
      for (int n = 0; n < 4; ++n)
        acc[i][n] = __builtin_amdgcn_mfma_f32_16x16x32_bf16(av[i], bv[n], acc[i][n], 0, 0, 0);
    __builtin_amdgcn_s_setprio(0);
    __builtin_amdgcn_sched_barrier(0);
    barrier_mem();

    // ---- phase 1: read A4-7 early, issue B-halves of t+3, vmcnt(8), barrier, MFMA ----
#pragma unroll
    for (int i = 0; i < 4; ++i) aw[i] = *(const bf16x8*)(aB + offA[4 + i]);
    if (t < nt - 3) {
      STG((s0 + 14) & 15, 2, t + 3);
      STG((s0 + 15) & 15, 3, t + 3);
      wait_vmcnt<8>();          // step t+1 fully landed; t+2,t+3 in flight
    } else if (t == nt - 3) {
      wait_vmcnt<4>();          // step t+1 landed; t+2 in flight
    } else if (t == nt - 2) {
      wait_vmcnt<0>();          // final step landed
    }
    barrier_mem();
    __builtin_amdgcn_s_setprio(1);
#pragma unroll
    for (int i = 0; i < 4; ++i)
#pragma unroll
      for (int n = 0; n < 4; ++n)
        acc[4 + i][n] = __builtin_amdgcn_mfma_f32_16x16x32_bf16(aw[i], bv[n], acc[4 + i][n], 0, 0, 0);
    __builtin_amdgcn_s_setprio(0);
    __builtin_amdgcn_sched_barrier(0);
    barrier_mem();

    s0 = (s0 + 4) & 15;
  }

  // epilogue: C/D layout col=lane&15, row=(lane>>4)*4+j
#pragma unroll
  for (int n = 0; n < 4; ++n) {
    int col = bn0 + wn * 64 + n * 16 + lrow;
    if (col < N) {
      float bv2 = bias[col];
#pragma unroll
      for (int m = 0; m < 8; ++m) {
#pragma unroll
        for (int j = 0; j < 4; ++j) {
          int row = bm0 + wm * 128 + m * 16 + lj * 4 + j;
          float v = acc[m][n][j] + bv2;
          if (BF16OUT)
            ((unsigned short*)Cv)[(size_t)row * N + col] = f2bf(v);
          else
            ((float*)Cv)[(size_t)row * N + col] = v;
        }
      }
    }
  }
}

// stage-1 dual GEMM: grid 224 = 7(N) x 16(M) x 2(tensor), XCD-chunked (224%8==0)
__global__ __launch_bounds__(512, 2) void gemm_dual_256(
    const unsigned short* A0, const unsigned short* B0, const float* bias0, unsigned short* C0,
    const unsigned short* A1, const unsigned short* B1, const float* bias1, unsigned short* C1) {
  __shared__ char lds[131072];
  int wg = (blockIdx.x & 7) * 28 + (blockIdx.x >> 3);   // contiguous chunk per XCD
  int bz = wg >= 112;
  wg -= bz * 112;
  int by = wg / 7, bx = wg % 7;
  const unsigned short* A = bz ? A1 : A0;
  const unsigned short* B = bz ? B1 : B0;
  const float* bias = bz ? bias1 : bias0;
  unsigned short* C = bz ? C1 : C0;
  gemm256_core<true>(A, B, bias, C, lds, MM, D0D1, D0D1 / 32, by * 256, bx * 256);
}

// stage-3 GEMM: grid 192 = 12(N) x 16(M), XCD-chunked (192%8==0)
__global__ __launch_bounds__(512, 2) void gemm_out_256(
    const unsigned short* A, const unsigned short* B, const float* bias, float* C) {
  __shared__ char lds[131072];
  int wg = (blockIdx.x & 7) * 24 + (blockIdx.x >> 3);
  int by = wg / 12, bx = wg % 12;
  gemm256_core<false>(A, B, bias, C, lds, NOUT, MM, MM / 32, by * 256, bx * 256);
}

// ---------- stage 2: h in registers, async double-buffered weight staging ----------
__global__ __launch_bounds__(256, 2) void chunk_fuse2(
    const unsigned short* __restrict__ hb0, const unsigned short* __restrict__ hb1,
    const unsigned short* __restrict__ mWP, unsigned short* __restrict__ zb) {
  const int c = blockIdx.x, bt = blockIdx.y;
  __shared__ unsigned short wlds[2][WRANK];
  const int tid = threadIdx.x, wave = tid >> 6, lane = tid & 63;
  const int lrow = lane & 15, lj = lane >> 4;

  bf16x8 bzero;
  bzero = (__bf16)0.0f;

  bf16x8 a0[2][3], a1[2][3];
#pragma unroll
  for (int m = 0; m < 2; ++m)
#pragma unroll
    for (int kf = 0; kf < 3; ++kf) {
      int col = kf * 32 + lj * 8;
      bool valid = col < CSIZE;
      int row = bt * 128 + wave * 32 + m * 16 + lrow;
      size_t base = (size_t)row * MM + c * CSIZE + (valid ? col : 0);
      bf16x8 v0 = *(const bf16x8*)(hb0 + base);
      bf16x8 v1 = *(const bf16x8*)(hb1 + base);
      a0[m][kf] = valid ? v0 : bzero;
      a1[m][kf] = valid ? v1 : bzero;
    }

  const unsigned short* wsrc = mWP + (size_t)(c * RANK) * WRANK;
  auto STAGE = [&](int buf, int r) {
    const unsigned short* src = wsrc + (size_t)r * WRANK;
    char* dstb = (char*)&wlds[buf][0];
#pragma unroll
    for (int k = 0; k < 7; ++k) {
      int i = k * 256 + tid;
      if (i < WCH)
        gload_lds16(src + (size_t)i * 8, dstb + (k * 256 + wave * 64) * 16);
    }
  };

  f32x4 zacc[2][5];
#pragma unroll
  for (int m = 0; m < 2; ++m)
#pragma unroll
    for (int n = 0; n < 5; ++n) zacc[m][n] = 0.f;

  STAGE(0, 0);
  for (int r = 0; r < RANK; ++r) {
    int cur = r & 1;
    if (r < RANK - 1) {
      STAGE(cur ^ 1, r + 1);
      asm volatile("s_waitcnt vmcnt(7)" ::: "memory");
    } else {
      asm volatile("s_waitcnt vmcnt(0)" ::: "memory");
    }
    __builtin_amdgcn_s_barrier();

    float bs0[5], bs1[5];
#pragma unroll
    for (int n = 0; n < 5; ++n) {
      int s = n * 16 + lrow;
      bs0[n] = bf2f(wlds[cur][0 * WTEN + 80 * WST + s]);
      bs1[n] = bf2f(wlds[cur][1 * WTEN + 80 * WST + s]);
    }

#pragma unroll
    for (int m = 0; m < 2; ++m) {
      f32x4 y0[5], y1[5];
#pragma unroll
      for (int n = 0; n < 5; ++n) { y0[n] = 0.f; y1[n] = 0.f; }
#pragma unroll
      for (int kf = 0; kf < 3; ++kf) {
        int colb = kf * 32 + lj * 8;
        bool bvalid = colb < WST;
        int cb = bvalid ? colb : 0;
#pragma unroll
        for (int n = 0; n < 5; ++n) {
          int tt = n * 16 + lrow;
          bf16x8 b0 = *(const bf16x8*)&wlds[cur][0 * WTEN + tt * WST + cb];
          bf16x8 b1 = *(const bf16x8*)&wlds[cur][1 * WTEN + tt * WST + cb];
          if (!bvalid) { b0 = bzero; b1 = bzero; }
          y0[n] = __builtin_amdgcn_mfma_f32_16x16x32_bf16(a0[m][kf], b0, y0[n], 0, 0, 0);
          y1[n] = __builtin_amdgcn_mfma_f32_16x16x32_bf16(a1[m][kf], b1, y1[n], 0, 0, 0);
        }
      }
#pragma unroll
      for (int n = 0; n < 5; ++n)
#pragma unroll
        for (int j = 0; j < 4; ++j)
          zacc[m][n][j] += (y0[n][j] + bs0[n]) * (y1[n][j] + bs1[n]);
    }
    __builtin_amdgcn_s_barrier();
  }

#pragma unroll
  for (int m = 0; m < 2; ++m) {
    float g[5][4];
    float ssj[4] = {0.f, 0.f, 0.f, 0.f};
#pragma unroll
    for (int n = 0; n < 5; ++n)
#pragma unroll
      for (int j = 0; j < 4; ++j) {
        float v = zacc[m][n][j];
        float a = sqrtf(fabsf(v));
        float gv = v < 0.f ? -a : a;
        g[n][j] = gv;
        ssj[j] += gv * gv;
      }
#pragma unroll
    for (int j = 0; j < 4; ++j) {
      float s = ssj[j];
      s += __shfl_xor(s, 1);
      s += __shfl_xor(s, 2);
      s += __shfl_xor(s, 4);
      s += __shfl_xor(s, 8);
      float nrm = sqrtf(s);
      nrm = nrm > 1e-12f ? nrm : 1e-12f;
      ssj[j] = 1.f / nrm;
    }
#pragma unroll
    for (int n = 0; n < 5; ++n) {
      int scol = n * 16 + lrow;
#pragma unroll
      for (int j = 0; j < 4; ++j) {
        int row = bt * 128 + wave * 32 + m * 16 + lj * 4 + j;
        zb[(size_t)row * MM + c * CSIZE + scol] = f2bf(g[n][j] * ssj[j]);
      }
    }
  }
}

// ---------- workspace layout (bytes) ----------
#define OFF_XB0   ((size_t)0)
#define OFF_XB1   (OFF_XB0 + (size_t)BATCH * D0D1 * 2)
#define OFF_WB0   (OFF_XB1 + (size_t)BATCH * D0D1 * 2)
#define OFF_WB1   (OFF_WB0 + (size_t)MM * D0D1 * 2)
#define OFF_WOUTB (OFF_WB1 + (size_t)MM * D0D1 * 2)
#define OFF_HB0   (OFF_WOUTB + (size_t)NOUT * MM * 2)
#define OFF_HB1   (OFF_HB0 + (size_t)BATCH * MM * 2)
#define OFF_ZB    (OFF_HB1 + (size_t)BATCH * MM * 2)
#define WS_NEED   (OFF_ZB + (size_t)BATCH * MM * 2)
#define OFF_MWP   OFF_XB0   // mWP aliases xb0, packed after gemm_dual consumed it

extern "C" void kernel_launch(void* const* d_in, const int* in_sizes, int n_in,
                              void* d_out, int out_size, void* d_ws, size_t ws_size,
                              hipStream_t stream) {
  const float* x0   = (const float*)d_in[0];
  const float* x1   = (const float*)d_in[1];
  const float* W0   = (const float*)d_in[2];
  const float* b0   = (const float*)d_in[3];
  const float* W1   = (const float*)d_in[4];
  const float* b1   = (const float*)d_in[5];
  const float* mW0  = (const float*)d_in[6];
  const float* mb0  = (const float*)d_in[7];
  const float* mW1  = (const float*)d_in[8];
  const float* mb1  = (const float*)d_in[9];
  const float* Wout = (const float*)d_in[10];
  const float* bout = (const float*)d_in[11];

  if (ws_size < WS_NEED) return;

  char* ws = (char*)d_ws;
  unsigned short* xb0   = (unsigned short*)(ws + OFF_XB0);
  unsigned short* xb1   = (unsigned short*)(ws + OFF_XB1);
  unsigned short* Wb0   = (unsigned short*)(ws + OFF_WB0);
  unsigned short* Wb1   = (unsigned short*)(ws + OFF_WB1);
  unsigned short* Woutb = (unsigned short*)(ws + OFF_WOUTB);
  unsigned short* hb0   = (unsigned short*)(ws + OFF_HB0);
  unsigned short* hb1   = (unsigned short*)(ws + OFF_HB1);
  unsigned short* zb    = (unsigned short*)(ws + OFF_ZB);
  unsigned short* mWP   = (unsigned short*)(ws + OFF_MWP);

  auto cast = [&](const float* s, unsigned short* d, int n) {
    int blocks = (n / 8 + 255) / 256;
    hipLaunchKernelGGL(cast_bf16_k, dim3(blocks), dim3(256), 0, stream, s, d, n);
  };
  cast(x0, xb0, BATCH * D0D1);
  cast(x1, xb1, BATCH * D0D1);
  cast(W0, Wb0, MM * D0D1);
  cast(W1, Wb1, MM * D0D1);
  cast(Wout, Woutb, NOUT * MM);

  // stage 1: h0,h1 = x@W^T + b  -> bf16 [4096][1600]
  hipLaunchKernelGGL(gemm_dual_256, dim3(224), dim3(512), 0, stream,
                     xb0, Wb0, b0, hb0, xb1, Wb1, b1, hb1);

  // pack mW+mb (into xb0's space, now free)
  hipLaunchKernelGGL(cast_mwp_k, dim3((WCH + 255) / 256, RANK, NCHUNKS), dim3(256), 0, stream,
                     mW0, mb0, mW1, mb1, mWP);

  // stage 2: chunk MM + bilinear + signed sqrt + L2 norm -> zb bf16
  hipLaunchKernelGGL(chunk_fuse2, dim3(NCHUNKS, BATCH / 128), dim3(256), 0, stream,
                     hb0, hb1, mWP, zb);

  // stage 3: out = zn@Wout^T + bout -> f32 [4096][3000]
  hipLaunchKernelGGL(gemm_out_256, dim3(192), dim3(512), 0, stream,
                     zb, Woutb, bout, (float*)d_out);
}

// Round 8
// 212.419 us; speedup vs baseline: 1.5825x; 1.0572x over previous
//
#include <hip/hip_runtime.h>

typedef unsigned int uint32;
typedef __bf16 bf16x8 __attribute__((ext_vector_type(8)));
typedef float f32x4 __attribute__((ext_vector_type(4)));

typedef __attribute__((address_space(1))) unsigned int as1_uint;
typedef __attribute__((address_space(3))) unsigned int as3_uint;

// ---------- constants ----------
#define BATCH 4096
#define D0D1 2048
#define MM 1600
#define NCHUNKS 20
#define RANK 15
#define CSIZE 80
#define TDIM 1200   // SIZE*RANK
#define NOUT 3000

// packed weight layout for stage 2 (unchanged)
#define WST 88
#define WTROWS 81
#define WTEN (WTROWS * WST)
#define WRANK (2 * WTEN)
#define WCH (WRANK * 2 / 16)

__device__ __forceinline__ unsigned short f2bf(float f) {
  unsigned int u = __builtin_bit_cast(unsigned int, f);
  u = (u + 0x7fffu + ((u >> 16) & 1u)) >> 16;
  return (unsigned short)u;
}
__device__ __forceinline__ float bf2f(unsigned short u) {
  return __builtin_bit_cast(float, (uint32)u << 16);
}

__device__ __forceinline__ void gload_lds16(const void* g, void* lds) {
  __builtin_amdgcn_global_load_lds((as1_uint*)g, (as3_uint*)lds, 16, 0, 0);
}

template <int N>
__device__ __forceinline__ void wait_vmcnt() {
  asm volatile("s_waitcnt vmcnt(%0)" :: "n"(N) : "memory");
}
__device__ __forceinline__ void barrier_mem() {
  asm volatile("s_barrier" ::: "memory");
}

// ---------- fused cast f32 -> bf16 for all 5 tensors (1 launch) ----------
// vec8 boundaries: x0 1048576 | x1 2097152 | W0 2506752 | W1 2916352 | Wout 3516352
#define CV_X0 1048576
#define CV_X1 2097152
#define CV_W0 2506752
#define CV_W1 2916352
#define CV_WO 3516352
__global__ __launch_bounds__(256) void cast_all_k(
    const float* __restrict__ x0, const float* __restrict__ x1,
    const float* __restrict__ W0, const float* __restrict__ W1,
    const float* __restrict__ Wout,
    unsigned short* __restrict__ xb0, unsigned short* __restrict__ xb1,
    unsigned short* __restrict__ Wb0, unsigned short* __restrict__ Wb1,
    unsigned short* __restrict__ Woutb) {
  int v = blockIdx.x * 256 + threadIdx.x;
  if (v >= CV_WO) return;
  const float* s;
  unsigned short* d;
  int off;
  if (v < CV_X0)      { s = x0;   d = xb0;   off = v; }
  else if (v < CV_X1) { s = x1;   d = xb1;   off = v - CV_X0; }
  else if (v < CV_W0) { s = W0;   d = Wb0;   off = v - CV_X1; }
  else if (v < CV_W1) { s = W1;   d = Wb1;   off = v - CV_W0; }
  else                { s = Wout; d = Woutb; off = v - CV_W1; }
  size_t i = (size_t)off * 8;
  float4 v0 = *(const float4*)(s + i);
  float4 v1 = *(const float4*)(s + i + 4);
  uint4 o;
  o.x = (uint32)f2bf(v0.x) | ((uint32)f2bf(v0.y) << 16);
  o.y = (uint32)f2bf(v0.z) | ((uint32)f2bf(v0.w) << 16);
  o.z = (uint32)f2bf(v1.x) | ((uint32)f2bf(v1.y) << 16);
  o.w = (uint32)f2bf(v1.z) | ((uint32)f2bf(v1.w) << 16);
  *(uint4*)(d + i) = o;
}

// ---------- pack mW + mb into padded conflict-free layout (unchanged) ----------
__global__ __launch_bounds__(256) void cast_mwp_k(
    const float* __restrict__ mW0, const float* __restrict__ mb0,
    const float* __restrict__ mW1, const float* __restrict__ mb1,
    unsigned short* __restrict__ mWP) {
  const int c = blockIdx.z, r = blockIdx.y;
  int i = blockIdx.x * 256 + threadIdx.x;
  if (i >= WCH) return;
  int e = i * 8;
  int tensor = e / WTEN;
  int rem = e - tensor * WTEN;
  int row = rem / WST;
  int col0 = rem - row * WST;

  float v[8];
  if (col0 >= CSIZE) {
#pragma unroll
    for (int k = 0; k < 8; ++k) v[k] = 0.f;
  } else if (row < CSIZE) {
    const float* src = (tensor ? mW1 : mW0) +
                       ((size_t)c * TDIM + (size_t)r * CSIZE + row) * CSIZE + col0;
#pragma unroll
    for (int k = 0; k < 8; ++k) v[k] = src[k];
  } else {
    const float* src = (tensor ? mb1 : mb0) + (size_t)c * TDIM + (size_t)r * CSIZE + col0;
#pragma unroll
    for (int k = 0; k < 8; ++k) v[k] = src[k];
  }
  uint4 o;
  o.x = (uint32)f2bf(v[0]) | ((uint32)f2bf(v[1]) << 16);
  o.y = (uint32)f2bf(v[2]) | ((uint32)f2bf(v[3]) << 16);
  o.z = (uint32)f2bf(v[4]) | ((uint32)f2bf(v[5]) << 16);
  o.w = (uint32)f2bf(v[6]) | ((uint32)f2bf(v[7]) << 16);
  *(uint4*)(mWP + ((size_t)(c * RANK + r)) * WRANK + e) = o;
}

// ---------- NT GEMM core v6: 256x256, BK=64, dbuf, ONE barrier per K-tile ----------
// 8 waves (2M x 4N); wave owns 128x64 C. Buffer = A[256][64] (32KB) + B[256][64]
// (32KB) = 64KB; x2 = 128KB. Granule swizzle kg ^= (row&7): each of 8 granule
// positions gets exactly 8 lanes per b128 read -> zero excess bank conflict.
// Per tile: {ds_read 12 frags ks0; STG-A(next); 32 MFMA ks0; ds_read 12 ks1;
// STG-B(next); 32 MFMA ks1; vmcnt(0); s_barrier}. Compiler interleaves ks1
// reads into the ks0 MFMA cluster (fine lgkm counts); vmcnt(0) is hidden under
// the ks1 cluster (B-STG issued before it, A-STG a full cluster earlier).
// Safety: within tile t all reads hit buf(t&1), all stages write buf^1; t-1's
// reads completed (lgkm before consuming MFMA) before t-1's closing barrier.
template <bool BF16OUT>
__device__ __forceinline__ void gemm256_core(const unsigned short* __restrict__ A,
                                             const unsigned short* __restrict__ B,
                                             const float* __restrict__ bias,
                                             void* __restrict__ Cv,
                                             char* lds, int N, int K, int nt,
                                             int bm0, int bn0) {
  const int tid = threadIdx.x;
  const int wave = tid >> 6, lane = tid & 63;
  const int wm = wave >> 2, wn = wave & 3;
  const int lrow = lane & 15, lj = lane >> 4;

  // staging source byte offsets: 4 granules each of A and B per thread per tile
  uint32 eA[4], eB[4];
#pragma unroll
  for (int q = 0; q < 4; ++q) {
    int g = q * 512 + tid;                 // granule 0..2047 within 32KB half
    int r = g >> 3;                        // row 0..255
    int kg = (g & 7) ^ (r & 7);            // inverse swizzle on the source side
    eA[q] = (uint32)((bm0 + r) * K + kg * 8) * 2;
    int rb = bn0 + r;
    if (rb > N - 1) rb = N - 1;            // clamp keeps ragged-N loads in-bounds
    eB[q] = (uint32)(rb * K + kg * 8) * 2;
  }
  // swizzled ds_read byte offsets: offA[ks][m], offB[ks][n]
  int offA[2][8], offB[2][4];
#pragma unroll
  for (int m = 0; m < 8; ++m) {
    int row = wm * 128 + m * 16 + lrow;
#pragma unroll
    for (int ks = 0; ks < 2; ++ks) {
      int kg = (ks * 4 + lj) ^ (row & 7);
      offA[ks][m] = (row * 8 + kg) * 16;
    }
  }
#pragma unroll
  for (int n = 0; n < 4; ++n) {
    int row = wn * 64 + n * 16 + lrow;
#pragma unroll
    for (int ks = 0; ks < 2; ++ks) {
      int kg = (ks * 4 + lj) ^ (row & 7);
      offB[ks][n] = 32768 + (row * 8 + kg) * 16;
    }
  }

  f32x4 acc[8][4];
#pragma unroll
  for (int m = 0; m < 8; ++m)
#pragma unroll
    for (int n = 0; n < 4; ++n) acc[m][n] = 0.f;

  const char* Ab = (const char*)A;
  const char* Bb = (const char*)B;
  auto STGA = [&](int t, int buf) {
    char* base = lds + buf * 65536;
    uint32 kb = (uint32)t * 128;
#pragma unroll
    for (int q = 0; q < 4; ++q)
      gload_lds16(Ab + eA[q] + kb, base + (q * 512 + tid) * 16);
  };
  auto STGB = [&](int t, int buf) {
    char* base = lds + buf * 65536 + 32768;
    uint32 kb = (uint32)t * 128;
#pragma unroll
    for (int q = 0; q < 4; ++q)
      gload_lds16(Bb + eB[q] + kb, base + (q * 512 + tid) * 16);
  };

  // prologue: tile 0 -> buf 0
  STGA(0, 0);
  STGB(0, 0);
  wait_vmcnt<0>();
  barrier_mem();

  for (int t = 0; t < nt; ++t) {
    const int buf = t & 1;
    const char* base = lds + buf * 65536;
    bf16x8 av[8], bv[4];

    // ---- ks = 0 ----
#pragma unroll
    for (int n = 0; n < 4; ++n) bv[n] = *(const bf16x8*)(base + offB[0][n]);
#pragma unroll
    for (int m = 0; m < 8; ++m) av[m] = *(const bf16x8*)(base + offA[0][m]);
    if (t < nt - 1) STGA(t + 1, buf ^ 1);
#pragma unroll
    for (int m = 0; m < 8; ++m)
#pragma unroll
      for (int n = 0; n < 4; ++n)
        acc[m][n] = __builtin_amdgcn_mfma_f32_16x16x32_bf16(av[m], bv[n], acc[m][n], 0, 0, 0);

    // ---- ks = 1 ----
#pragma unroll
    for (int n = 0; n < 4; ++n) bv[n] = *(const bf16x8*)(base + offB[1][n]);
#pragma unroll
    for (int m = 0; m < 8; ++m) av[m] = *(const bf16x8*)(base + offA[1][m]);
    if (t < nt - 1) STGB(t + 1, buf ^ 1);
#pragma unroll
    for (int m = 0; m < 8; ++m)
#pragma unroll
      for (int n = 0; n < 4; ++n)
        acc[m][n] = __builtin_amdgcn_mfma_f32_16x16x32_bf16(av[m], bv[n], acc[m][n], 0, 0, 0);

    if (t < nt - 1) {
      wait_vmcnt<0>();     // next tile fully landed (drain hidden under ks1 MFMAs)
      barrier_mem();       // single barrier per K-tile
    }
  }

  // epilogue: C/D layout col=lane&15, row=(lane>>4)*4+j
#pragma unroll
  for (int n = 0; n < 4; ++n) {
    int col = bn0 + wn * 64 + n * 16 + lrow;
    if (col < N) {
      float bv2 = bias[col];
#pragma unroll
      for (int m = 0; m < 8; ++m) {
#pragma unroll
        for (int j = 0; j < 4; ++j) {
          int row = bm0 + wm * 128 + m * 16 + lj * 4 + j;
          float v = acc[m][n][j] + bv2;
          if (BF16OUT)
            ((unsigned short*)Cv)[(size_t)row * N + col] = f2bf(v);
          else
            ((float*)Cv)[(size_t)row * N + col] = v;
        }
      }
    }
  }
}

// stage-1 dual GEMM: grid 224 = 7(N) x 16(M) x 2(tensor), XCD-chunked (224%8==0)
__global__ __launch_bounds__(512, 2) void gemm_dual_256(
    const unsigned short* A0, const unsigned short* B0, const float* bias0, unsigned short* C0,
    const unsigned short* A1, const unsigned short* B1, const float* bias1, unsigned short* C1) {
  __shared__ char lds[131072];
  int wg = (blockIdx.x & 7) * 28 + (blockIdx.x >> 3);   // contiguous chunk per XCD
  int bz = wg >= 112;
  wg -= bz * 112;
  int by = wg / 7, bx = wg % 7;
  const unsigned short* A = bz ? A1 : A0;
  const unsigned short* B = bz ? B1 : B0;
  const float* bias = bz ? bias1 : bias0;
  unsigned short* C = bz ? C1 : C0;
  gemm256_core<true>(A, B, bias, C, lds, MM, D0D1, D0D1 / 64, by * 256, bx * 256);
}

// stage-3 GEMM: grid 192 = 12(N) x 16(M), XCD-chunked (192%8==0)
__global__ __launch_bounds__(512, 2) void gemm_out_256(
    const unsigned short* A, const unsigned short* B, const float* bias, float* C) {
  __shared__ char lds[131072];
  int wg = (blockIdx.x & 7) * 24 + (blockIdx.x >> 3);
  int by = wg / 12, bx = wg % 12;
  gemm256_core<false>(A, B, bias, C, lds, NOUT, MM, MM / 64, by * 256, bx * 256);
}

// ---------- stage 2: h in registers, async double-buffered weight staging ----------
__global__ __launch_bounds__(256, 2) void chunk_fuse2(
    const unsigned short* __restrict__ hb0, const unsigned short* __restrict__ hb1,
    const unsigned short* __restrict__ mWP, unsigned short* __restrict__ zb) {
  const int c = blockIdx.x, bt = blockIdx.y;
  __shared__ unsigned short wlds[2][WRANK];
  const int tid = threadIdx.x, wave = tid >> 6, lane = tid & 63;
  const int lrow = lane & 15, lj = lane >> 4;

  bf16x8 bzero;
  bzero = (__bf16)0.0f;

  bf16x8 a0[2][3], a1[2][3];
#pragma unroll
  for (int m = 0; m < 2; ++m)
#pragma unroll
    for (int kf = 0; kf < 3; ++kf) {
      int col = kf * 32 + lj * 8;
      bool valid = col < CSIZE;
      int row = bt * 128 + wave * 32 + m * 16 + lrow;
      size_t base = (size_t)row * MM + c * CSIZE + (valid ? col : 0);
      bf16x8 v0 = *(const bf16x8*)(hb0 + base);
      bf16x8 v1 = *(const bf16x8*)(hb1 + base);
      a0[m][kf] = valid ? v0 : bzero;
      a1[m][kf] = valid ? v1 : bzero;
    }

  const unsigned short* wsrc = mWP + (size_t)(c * RANK) * WRANK;
  auto STAGE = [&](int buf, int r) {
    const unsigned short* src = wsrc + (size_t)r * WRANK;
    char* dstb = (char*)&wlds[buf][0];
#pragma unroll
    for (int k = 0; k < 7; ++k) {
      int i = k * 256 + tid;
      if (i < WCH)
        gload_lds16(src + (size_t)i * 8, dstb + (k * 256 + wave * 64) * 16);
    }
  };

  f32x4 zacc[2][5];
#pragma unroll
  for (int m = 0; m < 2; ++m)
#pragma unroll
    for (int n = 0; n < 5; ++n) zacc[m][n] = 0.f;

  STAGE(0, 0);
  for (int r = 0; r < RANK; ++r) {
    int cur = r & 1;
    if (r < RANK - 1) {
      STAGE(cur ^ 1, r + 1);
      asm volatile("s_waitcnt vmcnt(7)" ::: "memory");
    } else {
      asm volatile("s_waitcnt vmcnt(0)" ::: "memory");
    }
    __builtin_amdgcn_s_barrier();

    float bs0[5], bs1[5];
#pragma unroll
    for (int n = 0; n < 5; ++n) {
      int s = n * 16 + lrow;
      bs0[n] = bf2f(wlds[cur][0 * WTEN + 80 * WST + s]);
      bs1[n] = bf2f(wlds[cur][1 * WTEN + 80 * WST + s]);
    }

#pragma unroll
    for (int m = 0; m < 2; ++m) {
      f32x4 y0[5], y1[5];
#pragma unroll
      for (int n = 0; n < 5; ++n) { y0[n] = 0.f; y1[n] = 0.f; }
#pragma unroll
      for (int kf = 0; kf < 3; ++kf) {
        int colb = kf * 32 + lj * 8;
        bool bvalid = colb < WST;
        int cb = bvalid ? colb : 0;
#pragma unroll
        for (int n = 0; n < 5; ++n) {
          int tt = n * 16 + lrow;
          bf16x8 b0 = *(const bf16x8*)&wlds[cur][0 * WTEN + tt * WST + cb];
          bf16x8 b1 = *(const bf16x8*)&wlds[cur][1 * WTEN + tt * WST + cb];
          if (!bvalid) { b0 = bzero; b1 = bzero; }
          y0[n] = __builtin_amdgcn_mfma_f32_16x16x32_bf16(a0[m][kf], b0, y0[n], 0, 0, 0);
          y1[n] = __builtin_amdgcn_mfma_f32_16x16x32_bf16(a1[m][kf], b1, y1[n], 0, 0, 0);
        }
      }
#pragma unroll
      for (int n = 0; n < 5; ++n)
#pragma unroll
        for (int j = 0; j < 4; ++j)
          zacc[m][n][j] += (y0[n][j] + bs0[n]) * (y1[n][j] + bs1[n]);
    }
    __builtin_amdgcn_s_barrier();
  }

#pragma unroll
  for (int m = 0; m < 2; ++m) {
    float g[5][4];
    float ssj[4] = {0.f, 0.f, 0.f, 0.f};
#pragma unroll
    for (int n = 0; n < 5; ++n)
#pragma unroll
      for (int j = 0; j < 4; ++j) {
        float v = zacc[m][n][j];
        float a = sqrtf(fabsf(v));
        float gv = v < 0.f ? -a : a;
        g[n][j] = gv;
        ssj[j] += gv * gv;
      }
#pragma unroll
    for (int j = 0; j < 4; ++j) {
      float s = ssj[j];
      s += __shfl_xor(s, 1);
      s += __shfl_xor(s, 2);
      s += __shfl_xor(s, 4);
      s += __shfl_xor(s, 8);
      float nrm = sqrtf(s);
      nrm = nrm > 1e-12f ? nrm : 1e-12f;
      ssj[j] = 1.f / nrm;
    }
#pragma unroll
    for (int n = 0; n < 5; ++n) {
      int scol = n * 16 + lrow;
#pragma unroll
      for (int j = 0; j < 4; ++j) {
        int row = bt * 128 + wave * 32 + m * 16 + lj * 4 + j;
        zb[(size_t)row * MM + c * CSIZE + scol] = f2bf(g[n][j] * ssj[j]);
      }
    }
  }
}

// ---------- workspace layout (bytes) ----------
#define OFF_XB0   ((size_t)0)
#define OFF_XB1   (OFF_XB0 + (size_t)BATCH * D0D1 * 2)
#define OFF_WB0   (OFF_XB1 + (size_t)BATCH * D0D1 * 2)
#define OFF_WB1   (OFF_WB0 + (size_t)MM * D0D1 * 2)
#define OFF_WOUTB (OFF_WB1 + (size_t)MM * D0D1 * 2)
#define OFF_HB0   (OFF_WOUTB + (size_t)NOUT * MM * 2)
#define OFF_HB1   (OFF_HB0 + (size_t)BATCH * MM * 2)
#define OFF_ZB    (OFF_HB1 + (size_t)BATCH * MM * 2)
#define WS_NEED   (OFF_ZB + (size_t)BATCH * MM * 2)
#define OFF_MWP   OFF_XB0   // mWP aliases xb0, packed after gemm_dual consumed it

extern "C" void kernel_launch(void* const* d_in, const int* in_sizes, int n_in,
                              void* d_out, int out_size, void* d_ws, size_t ws_size,
                              hipStream_t stream) {
  const float* x0   = (const float*)d_in[0];
  const float* x1   = (const float*)d_in[1];
  const float* W0   = (const float*)d_in[2];
  const float* b0   = (const float*)d_in[3];
  const float* W1   = (const float*)d_in[4];
  const float* b1   = (const float*)d_in[5];
  const float* mW0  = (const float*)d_in[6];
  const float* mb0  = (const float*)d_in[7];
  const float* mW1  = (const float*)d_in[8];
  const float* mb1  = (const float*)d_in[9];
  const float* Wout = (const float*)d_in[10];
  const float* bout = (const float*)d_in[11];

  if (ws_size < WS_NEED) return;

  char* ws = (char*)d_ws;
  unsigned short* xb0   = (unsigned short*)(ws + OFF_XB0);
  unsigned short* xb1   = (unsigned short*)(ws + OFF_XB1);
  unsigned short* Wb0   = (unsigned short*)(ws + OFF_WB0);
  unsigned short* Wb1   = (unsigned short*)(ws + OFF_WB1);
  unsigned short* Woutb = (unsigned short*)(ws + OFF_WOUTB);
  unsigned short* hb0   = (unsigned short*)(ws + OFF_HB0);
  unsigned short* hb1   = (unsigned short*)(ws + OFF_HB1);
  unsigned short* zb    = (unsigned short*)(ws + OFF_ZB);
  unsigned short* mWP   = (unsigned short*)(ws + OFF_MWP);

  // all 5 f32->bf16 casts in one launch
  hipLaunchKernelGGL(cast_all_k, dim3((CV_WO + 255) / 256), dim3(256), 0, stream,
                     x0, x1, W0, W1, Wout, xb0, xb1, Wb0, Wb1, Woutb);

  // stage 1: h0,h1 = x@W^T + b  -> bf16 [4096][1600]
  hipLaunchKernelGGL(gemm_dual_256, dim3(224), dim3(512), 0, stream,
                     xb0, Wb0, b0, hb0, xb1, Wb1, b1, hb1);

  // pack mW+mb (into xb0's space, now free)
  hipLaunchKernelGGL(cast_mwp_k, dim3((WCH + 255) / 256, RANK, NCHUNKS), dim3(256), 0, stream,
                     mW0, mb0, mW1, mb1, mWP);

  // stage 2: chunk MM + bilinear + signed sqrt + L2 norm -> zb bf16
  hipLaunchKernelGGL(chunk_fuse2, dim3(NCHUNKS, BATCH / 128), dim3(256), 0, stream,
                     hb0, hb1, mWP, zb);

  // stage 3: out = zn@Wout^T + bout -> f32 [4096][3000]
  hipLaunchKernelGGL(gemm_out_256, dim3(192), dim3(512), 0, stream,
                     zb, Woutb, bout, (float*)d_out);
}